// Round 10
// baseline (234.306 us; speedup 1.0000x reference)
//
#include <hip/hip_runtime.h>
#include <hip/hip_bf16.h>
#include <stdint.h>

#define ALPHA 0.2f
#define LOG2E 1.4426950408889634f

typedef __attribute__((ext_vector_type(4))) float f32x4;
typedef __attribute__((ext_vector_type(8))) __bf16 bf16x8;
typedef __attribute__((ext_vector_type(8))) unsigned short u16x8;
typedef __attribute__((ext_vector_type(4))) unsigned short u16x4;
typedef __attribute__((ext_vector_type(4))) unsigned int u32x4;

static __device__ __forceinline__ unsigned short f2bf(float f) {
  unsigned u = __builtin_bit_cast(unsigned, f);
  u += 0x7FFFu + ((u >> 16) & 1u);   // RNE
  return (unsigned short)(u >> 16);
}
static __device__ __forceinline__ float bf2f(unsigned short h) {
  unsigned u = ((unsigned)h) << 16;
  return __builtin_bit_cast(float, u);
}
// raw v_exp_f32: computes 2^x (inputs are pre-scaled by log2e upstream)
static __device__ __forceinline__ float exp2_hw(float x) {
  float r; asm("v_exp_f32 %0, %1" : "=v"(r) : "v"(x)); return r;
}
// packed f32->bf16 RNE (no builtin on gfx950)
static __device__ __forceinline__ unsigned int cvt_pk_bf16(float lo, float hi) {
  unsigned int r; asm("v_cvt_pk_bf16_f32 %0, %1, %2" : "=v"(r) : "v"(lo), "v"(hi)); return r;
}
// async global->LDS, 16B per lane. LDS dest must be wave-uniform base + lane*16.
static __device__ __forceinline__ void gl_lds16(const void* g, void* lds) {
  __builtin_amdgcn_global_load_lds(
      (const __attribute__((address_space(1))) unsigned int*)g,
      (__attribute__((address_space(3))) unsigned int*)lds, 16, 0, 0);
}

// ================= k_prep: pack_bits + cast + transposes + wa =================
// pack_bits runs HERE (before whT1 exists) so its 64MB adj stream cannot evict
// whT1 from L2 between the gemm and attn (R8/R9 lesson: eviction cost attn +12%
// via L3-latency stage reads, invisible to FETCH_SIZE; moving pack first fixed it).
#define PREP_PACK_END 16384
#define PREP_CAST_END 17408
#define PREP_T1_END   17920
#define PREP_T2_END   18176
#define PREP_WA1_END  18688
#define PREP_GRID     18944

__global__ void k_prep(const int* __restrict__ adj, unsigned int* __restrict__ bits,
                       const float* __restrict__ x, unsigned short* __restrict__ xb,
                       const float* __restrict__ W1, unsigned short* __restrict__ w1t,
                       const float* __restrict__ W2, unsigned short* __restrict__ w2t,
                       const float* __restrict__ a1, float* __restrict__ wa1,
                       const float* __restrict__ a2, float* __restrict__ wa2) {
  __shared__ float tsh[32][33];
  const int b = blockIdx.x, tid = threadIdx.x;
  if (b < PREP_PACK_END) {
    // ---- pack_bits: quarter-row per block ----
    int row = b >> 2, qo = b & 3;
    const int4* ap = (const int4*)(adj + (size_t)row * 4096 + qo * 1024);
    int4 v = ap[tid];
    unsigned n = (unsigned)(v.x != 0) | ((unsigned)(v.y != 0) << 1) |
                 ((unsigned)(v.z != 0) << 2) | ((unsigned)(v.w != 0) << 3);
    unsigned char* nib = (unsigned char*)tsh;
    nib[tid] = (unsigned char)n;
    __syncthreads();
    if (tid < 32) {
      unsigned w = 0;
#pragma unroll
      for (int s = 0; s < 8; ++s) w |= ((unsigned)nib[tid * 8 + s]) << (4 * s);
      bits[(size_t)row * 128 + qo * 32 + tid] = w;
    }
  } else if (b < PREP_CAST_END) {
    int t = (b - PREP_PACK_END) * 256 + tid;
    const f32x4* p = (const f32x4*)(x + (long)t * 8);
    f32x4 va = p[0], vb = p[1];
    u16x8 o;
#pragma unroll
    for (int k = 0; k < 4; ++k) { o[k] = f2bf(va[k]); o[k + 4] = f2bf(vb[k]); }
    *(u16x8*)(xb + (long)t * 8) = o;
  } else if (b < PREP_T2_END) {
    const float* in; unsigned short* out; int K, N, bx, by, bz;
    if (b < PREP_T1_END) {
      int idx = b - PREP_CAST_END;           // 512 blocks: (16,8,4)
      bx = idx & 15; by = (idx >> 4) & 7; bz = idx >> 7;
      in = W1; out = w1t; K = 512; N = 256;
    } else {
      int idx = b - PREP_T1_END;             // 256 blocks: (32,8,1)
      bx = idx & 31; by = (idx >> 5) & 7; bz = 0;
      in = W2; out = w2t; K = 1024; N = 256;
    }
    long bs = (long)K * N;
    const float* inb = in + bz * bs;
    unsigned short* outb = out + bz * bs;
    int k0 = bx * 32, n0 = by * 32;
    int tx = tid & 31, ty = tid >> 5;
#pragma unroll
    for (int it = 0; it < 4; ++it)
      tsh[ty + it * 8][tx] = inb[(long)(k0 + ty + it * 8) * N + n0 + tx];
    __syncthreads();
#pragma unroll
    for (int it = 0; it < 4; ++it)
      outb[(long)(n0 + ty + it * 8) * K + k0 + tx] = f2bf(tsh[tx][ty + it * 8]);
  } else {
    const float* W; const float* a; float* wa; int headK;
    int bl;
    if (b < PREP_WA1_END) { bl = b - PREP_T2_END; W = W1; a = a1; wa = wa1; headK = 512; }
    else                  { bl = b - PREP_WA1_END; W = W2; a = a2; wa = wa2; headK = 1024; }
    const int F = 256;
    int w = (bl * 256 + tid) >> 6;
    int lane = tid & 63;
    int h = w / headK, fl = w % headK;
    const float* row = W + (size_t)w * F;
    const float* ah = a + (size_t)h * 2 * F;
    float s0 = 0.f, s1 = 0.f;
    for (int fo = lane; fo < F; fo += 64) {
      float wv = row[fo];
      s0 += wv * ah[fo];
      s1 += wv * ah[F + fo];
    }
#pragma unroll
    for (int off = 32; off; off >>= 1) {
      s0 += __shfl_xor(s0, off);
      s1 += __shfl_xor(s1, off);
    }
    if (lane == 0) {
      wa[(size_t)(h * 2 + 0) * headK + fl] = s0;
      wa[(size_t)(h * 2 + 1) * headK + fl] = s1;
    }
  }
}

// ================= pipelined gemm_wh body (attn4-style: stage-top, 1 barrier) =================
static __device__ __forceinline__ void gemm_wh_body(
    const unsigned short* __restrict__ A, const unsigned short* __restrict__ BT,
    unsigned short* __restrict__ whT, int K, int i0, int fbase, char* lds) {
  unsigned short* As = (unsigned short*)lds;            // 2 x 2048 shorts
  unsigned short* Bs = (unsigned short*)(lds + 8192);   // 2 x 4096 shorts
  const int tid = threadIdx.x, lane = tid & 63, wid = tid >> 6;
  const int q = lane >> 4, l15 = lane & 15;
  const int wm = wid >> 1, wn = wid & 1;
  f32x4 acc[2][4] = {};
  const unsigned short* aRow = A + (long)(i0 + (tid >> 2)) * K + (tid & 3) * 8;
  const int cid1 = 256 + tid;
  const unsigned short* bRow0 = BT + (long)(fbase + (tid >> 2)) * K + (tid & 3) * 8;
  const unsigned short* bRow1 = BT + (long)(fbase + (cid1 >> 2)) * K + (cid1 & 3) * 8;

#define GSTAGE(PAR, KK)                                                        \
  gl_lds16(aRow + (KK), lds + (PAR) * 4096 + tid * 16);                        \
  gl_lds16(bRow0 + (KK), lds + 8192 + (PAR) * 8192 + tid * 16);                \
  gl_lds16(bRow1 + (KK), lds + 8192 + (PAR) * 8192 + cid1 * 16);

  GSTAGE(0, 0)
  asm volatile("s_waitcnt vmcnt(0)" ::: "memory");
  __builtin_amdgcn_sched_barrier(0);
  __builtin_amdgcn_s_barrier();
  for (int kk = 0; kk < K; kk += 32) {
    const int par = (kk >> 5) & 1;
    if (kk + 32 < K) { GSTAGE(par ^ 1, kk + 32) }
    bf16x8 af[2], bfr[4];
#pragma unroll
    for (int mi = 0; mi < 2; ++mi)
      af[mi] = *(const bf16x8*)&As[par * 2048 + (wm * 32 + mi * 16 + l15) * 32 + q * 8];
#pragma unroll
    for (int ni = 0; ni < 4; ++ni)
      bfr[ni] = *(const bf16x8*)&Bs[par * 4096 + (wn * 64 + ni * 16 + l15) * 32 + q * 8];
    __builtin_amdgcn_s_setprio(1);
#pragma unroll
    for (int mi = 0; mi < 2; ++mi)
#pragma unroll
      for (int ni = 0; ni < 4; ++ni)
        acc[mi][ni] = __builtin_amdgcn_mfma_f32_16x16x32_bf16(af[mi], bfr[ni], acc[mi][ni], 0, 0, 0);
    __builtin_amdgcn_s_setprio(0);
    asm volatile("s_waitcnt vmcnt(0)" ::: "memory");   // stage(t+1) landed
    asm volatile("s_waitcnt lgkmcnt(0)" ::: "memory");
    __builtin_amdgcn_sched_barrier(0);
    __builtin_amdgcn_s_barrier();
    __builtin_amdgcn_sched_barrier(0);
  }
#undef GSTAGE
#pragma unroll
  for (int mi = 0; mi < 2; ++mi)
#pragma unroll
    for (int ni = 0; ni < 4; ++ni) {
      int ig = i0 + wm * 32 + mi * 16 + q * 4;
      int fg = fbase + wn * 64 + ni * 16 + l15;
      u16x4 v;
#pragma unroll
      for (int r = 0; r < 4; ++r) v[r] = f2bf(acc[mi][ni][r]);
      *(u16x4*)&whT[(long)fg * 4096 + ig] = v;
    }
}

// ================= k_l1: gemm_wh L1 (512) + matvec1 (256) =================
__global__ void __launch_bounds__(256, 4)
k_l1(const unsigned short* __restrict__ xb, const unsigned short* __restrict__ w1t,
     unsigned short* __restrict__ whT1, const float* __restrict__ wa,
     float* __restrict__ srcv, float* __restrict__ dstv, float* __restrict__ dstva) {
  __shared__ char lds[24576];
  const int b = blockIdx.x, tid = threadIdx.x;
  if (b < 512) {
    int i0 = (b & 63) * 64;
    int fbase = (b >> 7) * 256 + ((b >> 6) & 1) * 128;
    gemm_wh_body(xb, w1t, whT1, 512, i0, fbase, lds);
    return;
  }
  // ---- matvec1: src/dst[h][i] = x[i,:] . wa[h*2+v], pre-scaled by log2e ----
  const int mb = b - 512;
  int lane = tid & 63, wid = tid >> 6;
  float wv[8][8];
#pragma unroll
  for (int v = 0; v < 8; ++v)
#pragma unroll
    for (int j = 0; j < 8; ++j) wv[v][j] = wa[v * 512 + lane * 8 + j];
  int base = (mb * 4 + wid) * 4;
  for (int rr = 0; rr < 4; ++rr) {
    int i = base + rr;
    u16x8 xv = *(const u16x8*)(xb + (size_t)i * 512 + lane * 8);
    float xf[8];
#pragma unroll
    for (int j = 0; j < 8; ++j) xf[j] = bf2f(xv[j]);
    float s[8] = {};
#pragma unroll
    for (int v = 0; v < 8; ++v)
#pragma unroll
      for (int j = 0; j < 8; ++j) s[v] += xf[j] * wv[v][j];
#pragma unroll
    for (int v = 0; v < 8; ++v)
#pragma unroll
      for (int off = 32; off; off >>= 1) s[v] += __shfl_xor(s[v], off);
    if (lane == 0) {
#pragma unroll
      for (int h = 0; h < 4; ++h) {
        srcv[h * 4096 + i] = s[h * 2] * LOG2E;
        float d = s[h * 2 + 1] * LOG2E;
        dstv[h * 4096 + i] = d;
        dstva[h * 4096 + i] = ALPHA * d;
      }
    }
  }
}

// ================= k_l2: gemm_wh L2 (pipelined) + matvec2 =================
__global__ void __launch_bounds__(256, 4)
k_l2(const unsigned short* __restrict__ h1, const unsigned short* __restrict__ w2t,
     unsigned short* __restrict__ whT2, const float* __restrict__ wa,
     float* __restrict__ srcv, float* __restrict__ dstv, float* __restrict__ dstva) {
  __shared__ char lds[24576];
  const int b = blockIdx.x;
  if (b < 128) {
    int i0 = (b & 63) * 64;
    int fbase = ((b >> 6) & 1) * 128;
    gemm_wh_body(h1, w2t, whT2, 1024, i0, fbase, lds);
    return;
  }
  // ---- matvec2 ----
  const int mb = b - 128;
  int lane = threadIdx.x & 63, wid = threadIdx.x >> 6;
  float wv[2][16];
#pragma unroll
  for (int v = 0; v < 2; ++v)
#pragma unroll
    for (int j = 0; j < 16; ++j) wv[v][j] = wa[v * 1024 + lane * 16 + j];
  int base = (mb * 4 + wid) * 4;
  for (int rr = 0; rr < 4; ++rr) {
    int i = base + rr;
    u16x8 x0 = *(const u16x8*)(h1 + (size_t)i * 1024 + lane * 16);
    u16x8 x1 = *(const u16x8*)(h1 + (size_t)i * 1024 + lane * 16 + 8);
    float s0 = 0.f, s1 = 0.f;
#pragma unroll
    for (int j = 0; j < 8; ++j) {
      float a0 = bf2f(x0[j]), a1 = bf2f(x1[j]);
      s0 += a0 * wv[0][j] + a1 * wv[0][j + 8];
      s1 += a0 * wv[1][j] + a1 * wv[1][j + 8];
    }
#pragma unroll
    for (int off = 32; off; off >>= 1) {
      s0 += __shfl_xor(s0, off);
      s1 += __shfl_xor(s1, off);
    }
    if (lane == 0) {
      srcv[i] = s0 * LOG2E;
      float d = s1 * LOG2E;
      dstv[i] = d;
      dstva[i] = ALPHA * d;
    }
  }
}

// ---------------- fused attention GEMM: 8-wave (512-thread) variant of k_attn4 ----------------
// Identical algorithm/schedule/LDS to the proven R2 structure, but 8 waves/block:
// waves/SIMD doubles 2->4 at the same 2 blocks/CU (LDS 80 KB), per-wave work halves,
// P-gen still computed once per (i,j). Counted vmcnt(5): 4-instr stage drained,
// 5 prefetch loads (2 dz + 2 da + 1 mask) ride across the single per-step barrier.

#define STAGE(PAR)                                                             \
  _Pragma("unroll")                                                            \
  for (int it = 0; it < 4; ++it)                                               \
    gl_lds16(wh_head + sidx + it * 262144u,                                    \
             (char*)&Bs[PAR][0] + (it * 512 + tid) * 16);                      \
  sidx += 64;

#define PREFETCH(DZ, DA, WB)                                                   \
  DZ[0] = *(const f32x4*)(dzp);                                                \
  DZ[1] = *(const f32x4*)(dzp + 4);                                            \
  DA[0] = *(const f32x4*)(dap);                                                \
  DA[1] = *(const f32x4*)(dap + 4);                                            \
  WB = *browp;                                                                 \
  dzp += 64; dap += 64; browp += 2;

#define PCOMP(WB, DZ, DA)                                                      \
  {                                                                            \
    unsigned wbv = (WB >> shift) & 0xFFu;                                      \
    float pe[8];                                                               \
    _Pragma("unroll")                                                          \
    for (int jj = 0; jj < 8; ++jj) {                                           \
      float e = fmaxf(sm + DZ[jj >> 2][jj & 3], am + DA[jj >> 2][jj & 3]);     \
      e = (wbv & (1u << jj)) ? e : -1e30f;  /* exp2(-1e30)=0 */                \
      pe[jj] = exp2_hw(e);                                                     \
    }                                                                          \
    pvA[0] = cvt_pk_bf16(pe[0], pe[1]);                                        \
    pvA[1] = cvt_pk_bf16(pe[2], pe[3]);                                        \
    pvA[2] = cvt_pk_bf16(pe[4], pe[5]);                                        \
    pvA[3] = cvt_pk_bf16(pe[6], pe[7]);                                        \
    lsum += ((pe[0] + pe[1]) + (pe[2] + pe[3])) +                              \
            ((pe[4] + pe[5]) + (pe[6] + pe[7]));                               \
  }

#define PSTO(PAR)                                                              \
  *(u32x4*)&Ps[PAR][prow * 64 + (kq ^ (prow & 7)) * 8] = pvA;

#define DOMFMA(PAR)                                                            \
  {                                                                            \
    _Pragma("unroll")                                                          \
    for (int s = 0; s < 2; ++s) {                                              \
      bf16x8 af[2], bfr[4];                                                    \
      _Pragma("unroll")                                                        \
      for (int mi = 0; mi < 2; ++mi)                                           \
        af[mi] = *(const bf16x8*)&Ps[PAR][(wm * 32 + mi * 16 + l15) * 64 +     \
                                          ((s * 4 + q) ^ (l15 & 7)) * 8];      \
      _Pragma("unroll")                                                        \
      for (int ni = 0; ni < 4; ++ni) {                                         \
        int f = wn * 64 + ni * 16 + l15;                                       \
        int slot = (s * 4 + q) ^ (l15 & 7);                                    \
        bfr[ni] = *(const bf16x8*)&Bs[PAR][f * 64 + slot * 8];                 \
      }                                                                        \
      __builtin_amdgcn_s_setprio(1);                                           \
      _Pragma("unroll")                                                        \
      for (int mi = 0; mi < 2; ++mi)                                           \
        _Pragma("unroll")                                                      \
        for (int ni = 0; ni < 4; ++ni)                                         \
          acc[mi][ni] = __builtin_amdgcn_mfma_f32_16x16x32_bf16(               \
              af[mi], bfr[ni], acc[mi][ni], 0, 0, 0);                          \
      __builtin_amdgcn_s_setprio(0);                                           \
    }                                                                          \
  }

#define STEP_SYNC                                                              \
  asm volatile("s_waitcnt vmcnt(5)" ::: "memory");                             \
  asm volatile("s_waitcnt lgkmcnt(0)" ::: "memory");                           \
  __builtin_amdgcn_sched_barrier(0);                                           \
  __builtin_amdgcn_s_barrier();                                                \
  __builtin_amdgcn_sched_barrier(0);

#define BODY(PAR, DZC, DAC, WBC, DZN, DAN, WBN)                                \
  {                                                                            \
    STAGE(PAR ^ 1)                                                             \
    __builtin_amdgcn_sched_barrier(0); /* keep stage older than prefetch */    \
    PREFETCH(DZN, DAN, WBN)                                                    \
    PCOMP(WBC, DZC, DAC)                                                       \
    DOMFMA(PAR)                                                                \
    PSTO(PAR ^ 1)                                                              \
    STEP_SYNC                                                                  \
  }

template <int JS, int H, int OC>
__global__ void __launch_bounds__(512, 4)
k_attn8(const unsigned short* __restrict__ whT, const unsigned int* __restrict__ bits,
        const float* __restrict__ srcv, const float* __restrict__ dstv,
        const float* __restrict__ dstva,
        float* __restrict__ Opart, float* __restrict__ Lpart) {
  static_assert(H * JS == 8, "group size must be 8");
  __shared__ unsigned short Bs[2][256 * 64];  // 64 KB, XOR-swizzled 16B chunks
  __shared__ unsigned short Ps[2][64 * 64];   // 16 KB, XOR-swizzled 16B chunks
  const int tid = threadIdx.x, lane = tid & 63, wid = tid >> 6;   // wid 0..7
  const int q = lane >> 4, l15 = lane & 15;
  const int wm = wid & 1, wn = wid >> 1;      // wave -> (32-row half, 64-f quarter)
  const int bid = blockIdx.x;
  const int g = bid & 7;
  const int head = g & (H - 1);
  const int js = g / H;
  const int i0 = (bid >> 3) * 64;
  const int jbase = js * (4096 / JS);
  constexpr int JSTEPS = (4096 / JS) / 64;

  const unsigned short* wh_head = whT + (size_t)head * 256 * 4096;
  const int prow = tid & 63, kq = tid >> 6;   // P role: row, 8-j chunk (0..7)

  // ---- dmax prologue: max over this head's dst ----
  float dmax;
  {
    float* dred = (float*)&Ps[0][0];   // Ps unused until PSTO(0)
    const float* dp = dstv + head * 4096;
    f32x4 v0 = *(const f32x4*)(dp + tid * 8);
    f32x4 v1 = *(const f32x4*)(dp + tid * 8 + 4);
    float lm = fmaxf(fmaxf(fmaxf(v0[0], v0[1]), fmaxf(v0[2], v0[3])),
                     fmaxf(fmaxf(v1[0], v1[1]), fmaxf(v1[2], v1[3])));
#pragma unroll
    for (int off = 32; off; off >>= 1) lm = fmaxf(lm, __shfl_xor(lm, off));
    if (lane == 0) dred[wid] = lm;
    __syncthreads();
    float m01 = fmaxf(dred[0], dred[1]), m23 = fmaxf(dred[2], dred[3]);
    float m45 = fmaxf(dred[4], dred[5]), m67 = fmaxf(dred[6], dred[7]);
    dmax = fmaxf(fmaxf(m01, m23), fmaxf(m45, m67));
    __syncthreads();   // dred reads done before Ps is reused
  }

  float src_r = srcv[head * 4096 + i0 + prow];   // pre-scaled by log2e
  float m_r;
  { float xm = src_r + dmax; m_r = fmaxf(xm, ALPHA * xm); }
  const float sm = src_r - m_r;          // lrelu(s+d)-m = max(sm+d, am+alpha*d)
  const float am = ALPHA * src_r - m_r;
  float lsum = 0.f;
  f32x4 acc[2][4] = {};

  // 32-bit running offsets; stage source pre-swizzled (chunk ^= row&7)
  const int srow = tid >> 3;
  unsigned sidx = (unsigned)(srow * 4096 + jbase + ((tid & 7) ^ (srow & 7)) * 8);
  const float* dzp = dstv + head * 4096 + jbase + kq * 8;
  const float* dap = dstva + head * 4096 + jbase + kq * 8;
  const unsigned int* browp = bits + (size_t)(i0 + prow) * 128 + (jbase >> 5) + (kq >> 2);
  const int shift = (kq & 3) * 8;

  f32x4 dzA[2], daA[2], dzB[2], daB[2];
  unsigned wbA, wbB;
  u32x4 pvA;

  // ---- prologue: dz(0)->A, stage Bs[0], dz(1)->B, P(0)->Ps[0] ----
  PREFETCH(dzA, daA, wbA)
  __builtin_amdgcn_sched_barrier(0);
  STAGE(0)
  __builtin_amdgcn_sched_barrier(0);
  PREFETCH(dzB, daB, wbB)
  PCOMP(wbA, dzA, daA)   // waits dz(0); stage + dz(1) stay in flight
  PSTO(0)
  STEP_SYNC              // vmcnt(5): stage(0) done, dz(1) flying

  // ---- main loop: body T has parity T&1; JSTEPS-1 bodies total ----
  for (int t = 0; t < JSTEPS - 3; t += 2) {
    BODY(0, dzB, daB, wbB, dzA, daA, wbA)
    BODY(1, dzA, daA, wbA, dzB, daB, wbB)
  }
  BODY(0, dzB, daB, wbB, dzA, daA, wbA)  // T = JSTEPS-2 (even)
  DOMFMA(1)                              // final step, parity 1

  // ---- epilogue: row-sum partials + unnormalized O partials ----
  __syncthreads();
  float* Lred = (float*)&Ps[0][0];       // 8x64 floats; Ps dead after final DOMFMA
  Lred[kq * 64 + prow] = lsum;
  __syncthreads();
  if (tid < 64) {
    float s = 0.f;
#pragma unroll
    for (int k = 0; k < 8; ++k) s += Lred[k * 64 + tid];
    Lpart[(size_t)(js * H + head) * 4096 + i0 + tid] = s;
  }
  float* Ob = Opart + (size_t)js * 4096 * OC + head * 256;
#pragma unroll
  for (int mi = 0; mi < 2; ++mi)
#pragma unroll
    for (int ni = 0; ni < 4; ++ni) {
      int i = i0 + wm * 32 + mi * 16 + q * 4;
      int col = wn * 64 + ni * 16 + l15;
#pragma unroll
      for (int r = 0; r < 4; ++r)
        Ob[(size_t)(i + r) * OC + col] = acc[mi][ni][r];
    }
}

// ---------------- combine layer1: h1 = ELU((Op0+Op1)/l) as bf16 ----------------
__global__ void __launch_bounds__(256) k_comb1(const float* __restrict__ Op,
                                               const float* __restrict__ Lp,
                                               unsigned short* __restrict__ h1) {
  int gidx = blockIdx.x * 256 + threadIdx.x;  // 1M threads, 4 cols each
  int i = gidx >> 8, c0 = (gidx & 255) * 4;
  int h = c0 >> 8;
  float l = Lp[h * 4096 + i] + Lp[(4 + h) * 4096 + i];
  float inv = 1.f / l;
  f32x4 p0 = *(const f32x4*)(Op + (size_t)i * 1024 + c0);
  f32x4 p1 = *(const f32x4*)(Op + (size_t)4096 * 1024 + (size_t)i * 1024 + c0);
  u16x4 o;
#pragma unroll
  for (int r = 0; r < 4; ++r) {
    float v = (p0[r] + p1[r]) * inv;
    v = v > 0.f ? v : (__expf(v) - 1.f);
    o[r] = f2bf(v);
  }
  *(u16x4*)(h1 + (size_t)i * 1024 + c0) = o;
}

// ---------------- combine layer2: out = (sum Op_js)/l, fp32 ----------------
__global__ void __launch_bounds__(256) k_comb2(const float* __restrict__ Op,
                                               const float* __restrict__ Lp,
                                               float* __restrict__ out) {
  int gidx = blockIdx.x * 256 + threadIdx.x;  // 262144 threads, 4 cols each
  int i = gidx >> 6, c0 = (gidx & 63) * 4;
  float l = 0.f;
#pragma unroll
  for (int js = 0; js < 8; ++js) l += Lp[js * 4096 + i];
  f32x4 s = {0.f, 0.f, 0.f, 0.f};
#pragma unroll
  for (int js = 0; js < 8; ++js)
    s += *(const f32x4*)(Op + (size_t)js * 4096 * 256 + (size_t)i * 256 + c0);
  float inv = 1.f / l;
  f32x4 o;
#pragma unroll
  for (int r = 0; r < 4; ++r) o[r] = s[r] * inv;
  *(f32x4*)(out + (size_t)i * 256 + c0) = o;
}

extern "C" void kernel_launch(void* const* d_in, const int* in_sizes, int n_in,
                              void* d_out, int out_size, void* d_ws, size_t ws_size,
                              hipStream_t stream) {
  const float* x  = (const float*)d_in[0];
  const int* adj  = (const int*)d_in[1];
  const float* W1 = (const float*)d_in[2];
  const float* a1 = (const float*)d_in[3];
  const float* W2 = (const float*)d_in[4];
  const float* a2 = (const float*)d_in[5];

  char* ws = (char*)d_ws;
  size_t off = 0;
  auto alloc = [&](size_t bytes) {
    void* p = ws + off;
    off = (off + bytes + 255) & ~(size_t)255;
    return p;
  };
  unsigned int*   bits = (unsigned int*)  alloc((size_t)4096 * 128 * 4);    //  2 MB
  unsigned short* xb   = (unsigned short*)alloc((size_t)4096 * 512 * 2);    //  4 MB
  unsigned short* w1t  = (unsigned short*)alloc((size_t)4 * 256 * 512 * 2); //  1 MB
  unsigned short* w2t  = (unsigned short*)alloc((size_t)256 * 1024 * 2);    // .5 MB
  unsigned short* whT1 = (unsigned short*)alloc((size_t)1024 * 4096 * 2);   //  8 MB
  unsigned short* h1   = (unsigned short*)alloc((size_t)4096 * 1024 * 2);   //  8 MB
  unsigned short* whT2 = (unsigned short*)alloc((size_t)256 * 4096 * 2);    //  2 MB
  float* wa1  = (float*)alloc((size_t)8 * 512 * 4);
  float* wa2  = (float*)alloc((size_t)2 * 1024 * 4);
  float* src1 = (float*)alloc(4 * 4096 * 4);
  float* dst1 = (float*)alloc(4 * 4096 * 4);
  float* dst1a = (float*)alloc(4 * 4096 * 4);
  float* src2 = (float*)alloc(4096 * 4);
  float* dst2 = (float*)alloc(4096 * 4);
  float* dst2a = (float*)alloc(4096 * 4);
  float* Lp1  = (float*)alloc((size_t)8 * 4096 * 4);
  float* Lp2  = (float*)alloc((size_t)8 * 4096 * 4);
  float* Opart = (float*)alloc((size_t)2 * 4096 * 1024 * 4);  // 32 MB, reused by layer 2

  // 1. prep (pack_bits FIRST + cast + transposes + wa)
  k_prep<<<dim3(PREP_GRID), dim3(256), 0, stream>>>(
      adj, bits, x, xb, W1, w1t, W2, w2t, a1, wa1, a2, wa2);

  // 2-4. layer 1
  k_l1<<<dim3(768), dim3(256), 0, stream>>>(xb, w1t, whT1, wa1, src1, dst1, dst1a);
  k_attn8<2, 4, 1024><<<dim3(512), dim3(512), 0, stream>>>(whT1, bits, src1, dst1, dst1a, Opart, Lp1);
  k_comb1<<<dim3(4096), dim3(256), 0, stream>>>(Opart, Lp1, h1);

  // 5-7. layer 2
  k_l2<<<dim3(384), dim3(256), 0, stream>>>(h1, w2t, whT2, wa2, src2, dst2, dst2a);
  k_attn8<8, 1, 256><<<dim3(512), dim3(512), 0, stream>>>(whT2, bits, src2, dst2, dst2a, Opart, Lp2);
  k_comb2<<<dim3(1024), dim3(256), 0, stream>>>(Opart, Lp2, (float*)d_out);
}

// Round 11
// 225.993 us; speedup vs baseline: 1.0368x; 1.0368x over previous
//
#include <hip/hip_runtime.h>
#include <hip/hip_bf16.h>
#include <stdint.h>

#define ALPHA 0.2f
#define LOG2E 1.4426950408889634f

typedef __attribute__((ext_vector_type(4))) float f32x4;
typedef __attribute__((ext_vector_type(8))) __bf16 bf16x8;
typedef __attribute__((ext_vector_type(8))) unsigned short u16x8;
typedef __attribute__((ext_vector_type(4))) unsigned short u16x4;
typedef __attribute__((ext_vector_type(4))) unsigned int u32x4;

static __device__ __forceinline__ unsigned short f2bf(float f) {
  unsigned u = __builtin_bit_cast(unsigned, f);
  u += 0x7FFFu + ((u >> 16) & 1u);   // RNE
  return (unsigned short)(u >> 16);
}
static __device__ __forceinline__ float bf2f(unsigned short h) {
  unsigned u = ((unsigned)h) << 16;
  return __builtin_bit_cast(float, u);
}
// raw v_exp_f32: computes 2^x (inputs are pre-scaled by log2e upstream)
static __device__ __forceinline__ float exp2_hw(float x) {
  float r; asm("v_exp_f32 %0, %1" : "=v"(r) : "v"(x)); return r;
}
// packed f32->bf16 RNE (no builtin on gfx950)
static __device__ __forceinline__ unsigned int cvt_pk_bf16(float lo, float hi) {
  unsigned int r; asm("v_cvt_pk_bf16_f32 %0, %1, %2" : "=v"(r) : "v"(lo), "v"(hi)); return r;
}
// async global->LDS, 16B per lane. LDS dest must be wave-uniform base + lane*16.
static __device__ __forceinline__ void gl_lds16(const void* g, void* lds) {
  __builtin_amdgcn_global_load_lds(
      (const __attribute__((address_space(1))) unsigned int*)g,
      (__attribute__((address_space(3))) unsigned int*)lds, 16, 0, 0);
}

// ================= k_prep: pack_bits + cast + transposes + wa =================
// pack_bits runs HERE (before whT1 exists) so its 64MB adj stream cannot evict
// whT1 from L2 between the gemm and attn (R8/R9 lesson: eviction cost attn +12%
// via L3-latency stage reads, invisible to FETCH_SIZE; moving pack first fixed it).
#define PREP_PACK_END 16384
#define PREP_CAST_END 17408
#define PREP_T1_END   17920
#define PREP_T2_END   18176
#define PREP_WA1_END  18688
#define PREP_GRID     18944

__global__ void k_prep(const int* __restrict__ adj, unsigned int* __restrict__ bits,
                       const float* __restrict__ x, unsigned short* __restrict__ xb,
                       const float* __restrict__ W1, unsigned short* __restrict__ w1t,
                       const float* __restrict__ W2, unsigned short* __restrict__ w2t,
                       const float* __restrict__ a1, float* __restrict__ wa1,
                       const float* __restrict__ a2, float* __restrict__ wa2) {
  __shared__ float tsh[32][33];
  const int b = blockIdx.x, tid = threadIdx.x;
  if (b < PREP_PACK_END) {
    // ---- pack_bits: quarter-row per block ----
    int row = b >> 2, qo = b & 3;
    const int4* ap = (const int4*)(adj + (size_t)row * 4096 + qo * 1024);
    int4 v = ap[tid];
    unsigned n = (unsigned)(v.x != 0) | ((unsigned)(v.y != 0) << 1) |
                 ((unsigned)(v.z != 0) << 2) | ((unsigned)(v.w != 0) << 3);
    unsigned char* nib = (unsigned char*)tsh;
    nib[tid] = (unsigned char)n;
    __syncthreads();
    if (tid < 32) {
      unsigned w = 0;
#pragma unroll
      for (int s = 0; s < 8; ++s) w |= ((unsigned)nib[tid * 8 + s]) << (4 * s);
      bits[(size_t)row * 128 + qo * 32 + tid] = w;
    }
  } else if (b < PREP_CAST_END) {
    int t = (b - PREP_PACK_END) * 256 + tid;
    const f32x4* p = (const f32x4*)(x + (long)t * 8);
    f32x4 va = p[0], vb = p[1];
    u16x8 o;
#pragma unroll
    for (int k = 0; k < 4; ++k) { o[k] = f2bf(va[k]); o[k + 4] = f2bf(vb[k]); }
    *(u16x8*)(xb + (long)t * 8) = o;
  } else if (b < PREP_T2_END) {
    const float* in; unsigned short* out; int K, N, bx, by, bz;
    if (b < PREP_T1_END) {
      int idx = b - PREP_CAST_END;           // 512 blocks: (16,8,4)
      bx = idx & 15; by = (idx >> 4) & 7; bz = idx >> 7;
      in = W1; out = w1t; K = 512; N = 256;
    } else {
      int idx = b - PREP_T1_END;             // 256 blocks: (32,8,1)
      bx = idx & 31; by = (idx >> 5) & 7; bz = 0;
      in = W2; out = w2t; K = 1024; N = 256;
    }
    long bs = (long)K * N;
    const float* inb = in + bz * bs;
    unsigned short* outb = out + bz * bs;
    int k0 = bx * 32, n0 = by * 32;
    int tx = tid & 31, ty = tid >> 5;
#pragma unroll
    for (int it = 0; it < 4; ++it)
      tsh[ty + it * 8][tx] = inb[(long)(k0 + ty + it * 8) * N + n0 + tx];
    __syncthreads();
#pragma unroll
    for (int it = 0; it < 4; ++it)
      outb[(long)(n0 + ty + it * 8) * K + k0 + tx] = f2bf(tsh[tx][ty + it * 8]);
  } else {
    const float* W; const float* a; float* wa; int headK;
    int bl;
    if (b < PREP_WA1_END) { bl = b - PREP_T2_END; W = W1; a = a1; wa = wa1; headK = 512; }
    else                  { bl = b - PREP_WA1_END; W = W2; a = a2; wa = wa2; headK = 1024; }
    const int F = 256;
    int w = (bl * 256 + tid) >> 6;
    int lane = tid & 63;
    int h = w / headK, fl = w % headK;
    const float* row = W + (size_t)w * F;
    const float* ah = a + (size_t)h * 2 * F;
    float s0 = 0.f, s1 = 0.f;
    for (int fo = lane; fo < F; fo += 64) {
      float wv = row[fo];
      s0 += wv * ah[fo];
      s1 += wv * ah[F + fo];
    }
#pragma unroll
    for (int off = 32; off; off >>= 1) {
      s0 += __shfl_xor(s0, off);
      s1 += __shfl_xor(s1, off);
    }
    if (lane == 0) {
      wa[(size_t)(h * 2 + 0) * headK + fl] = s0;
      wa[(size_t)(h * 2 + 1) * headK + fl] = s1;
    }
  }
}

// ================= pipelined gemm_wh body, BK=64 (halved barrier count) =================
// A[4096,K]bf16 @ BT[f][K]bf16 -> whT[f][4096] bf16; block = 64 rows x 128 f.
// BK=64 halves steps vs R9 (L1 16->8, L2 64->16) since per-step fixed cost
// (barrier arrival skew + drain) dominates these short K-loops (R10 attn lesson).
// LDS 48 KB: As[2][64*64] @ 0/8192, Bs[2][128*64] @ 16384/32768.
// Layout = attn4's proven pattern: linear LDS dest, pre-swizzled global source
// (chunk ^= row&7), XOR-swizzled ds_read slot -> 2-way residual conflicts (free).
static __device__ __forceinline__ void gemm_wh_body(
    const unsigned short* __restrict__ A, const unsigned short* __restrict__ BT,
    unsigned short* __restrict__ whT, int K, int i0, int fbase, char* lds) {
  unsigned short* As = (unsigned short*)lds;            // 2 x 4096 shorts
  unsigned short* Bs = (unsigned short*)(lds + 16384);  // 2 x 8192 shorts
  const int tid = threadIdx.x, lane = tid & 63, wid = tid >> 6;
  const int q = lane >> 4, l15 = lane & 15;
  const int wm = wid >> 1, wn = wid & 1;
  f32x4 acc[2][4] = {};
  // stage sources, pre-swizzled chunk (c ^ row&7); LDS dest linear in thread order
  const int arow0 = tid >> 3, arow1 = arow0 + 32;
  const unsigned short* aSrc0 = A + (long)(i0 + arow0) * K + (((tid & 7) ^ (arow0 & 7)) * 8);
  const unsigned short* aSrc1 = A + (long)(i0 + arow1) * K + (((tid & 7) ^ (arow1 & 7)) * 8);
  const unsigned short* bSrc[4];
#pragma unroll
  for (int p = 0; p < 4; ++p) {
    int row = p * 32 + (tid >> 3);
    bSrc[p] = BT + (long)(fbase + row) * K + (((tid & 7) ^ (row & 7)) * 8);
  }

#define GSTAGE(PAR, KK)                                                        \
  gl_lds16(aSrc0 + (KK), lds + (PAR) * 8192 + tid * 16);                       \
  gl_lds16(aSrc1 + (KK), lds + (PAR) * 8192 + 4096 + tid * 16);                \
  _Pragma("unroll")                                                            \
  for (int p = 0; p < 4; ++p)                                                  \
    gl_lds16(bSrc[p] + (KK), lds + 16384 + (PAR) * 16384 + (p * 256 + tid) * 16);

  GSTAGE(0, 0)
  asm volatile("s_waitcnt vmcnt(0)" ::: "memory");
  __builtin_amdgcn_sched_barrier(0);
  __builtin_amdgcn_s_barrier();
  for (int kk = 0; kk < K; kk += 64) {
    const int par = (kk >> 6) & 1;
    if (kk + 64 < K) { GSTAGE(par ^ 1, kk + 64) }
#pragma unroll
    for (int s = 0; s < 2; ++s) {
      bf16x8 af[2], bfr[4];
#pragma unroll
      for (int mi = 0; mi < 2; ++mi) {
        int row = wm * 32 + mi * 16 + l15;
        af[mi] = *(const bf16x8*)&As[par * 4096 + row * 64 +
                                     (((s * 4 + q) ^ (l15 & 7)) * 8)];
      }
#pragma unroll
      for (int ni = 0; ni < 4; ++ni) {
        int f = wn * 64 + ni * 16 + l15;
        bfr[ni] = *(const bf16x8*)&Bs[par * 8192 + f * 64 +
                                      (((s * 4 + q) ^ (l15 & 7)) * 8)];
      }
      __builtin_amdgcn_s_setprio(1);
#pragma unroll
      for (int mi = 0; mi < 2; ++mi)
#pragma unroll
        for (int ni = 0; ni < 4; ++ni)
          acc[mi][ni] = __builtin_amdgcn_mfma_f32_16x16x32_bf16(af[mi], bfr[ni], acc[mi][ni], 0, 0, 0);
      __builtin_amdgcn_s_setprio(0);
    }
    asm volatile("s_waitcnt vmcnt(0)" ::: "memory");   // stage(t+1) landed
    asm volatile("s_waitcnt lgkmcnt(0)" ::: "memory");
    __builtin_amdgcn_sched_barrier(0);
    __builtin_amdgcn_s_barrier();
    __builtin_amdgcn_sched_barrier(0);
  }
#undef GSTAGE
#pragma unroll
  for (int mi = 0; mi < 2; ++mi)
#pragma unroll
    for (int ni = 0; ni < 4; ++ni) {
      int ig = i0 + wm * 32 + mi * 16 + q * 4;
      int fg = fbase + wn * 64 + ni * 16 + l15;
      u16x4 v;
#pragma unroll
      for (int r = 0; r < 4; ++r) v[r] = f2bf(acc[mi][ni][r]);
      *(u16x4*)&whT[(long)fg * 4096 + ig] = v;
    }
}

// ================= k_l1: gemm_wh L1 (512) + matvec1 (256) =================
__global__ void __launch_bounds__(256, 2)
k_l1(const unsigned short* __restrict__ xb, const unsigned short* __restrict__ w1t,
     unsigned short* __restrict__ whT1, const float* __restrict__ wa,
     float* __restrict__ srcv, float* __restrict__ dstv, float* __restrict__ dstva) {
  __shared__ char lds[49152];
  const int b = blockIdx.x, tid = threadIdx.x;
  if (b < 512) {
    int i0 = (b & 63) * 64;
    int fbase = (b >> 7) * 256 + ((b >> 6) & 1) * 128;
    gemm_wh_body(xb, w1t, whT1, 512, i0, fbase, lds);
    return;
  }
  // ---- matvec1: src/dst[h][i] = x[i,:] . wa[h*2+v], pre-scaled by log2e ----
  const int mb = b - 512;
  int lane = tid & 63, wid = tid >> 6;
  float wv[8][8];
#pragma unroll
  for (int v = 0; v < 8; ++v)
#pragma unroll
    for (int j = 0; j < 8; ++j) wv[v][j] = wa[v * 512 + lane * 8 + j];
  int base = (mb * 4 + wid) * 4;
  for (int rr = 0; rr < 4; ++rr) {
    int i = base + rr;
    u16x8 xv = *(const u16x8*)(xb + (size_t)i * 512 + lane * 8);
    float xf[8];
#pragma unroll
    for (int j = 0; j < 8; ++j) xf[j] = bf2f(xv[j]);
    float s[8] = {};
#pragma unroll
    for (int v = 0; v < 8; ++v)
#pragma unroll
      for (int j = 0; j < 8; ++j) s[v] += xf[j] * wv[v][j];
#pragma unroll
    for (int v = 0; v < 8; ++v)
#pragma unroll
      for (int off = 32; off; off >>= 1) s[v] += __shfl_xor(s[v], off);
    if (lane == 0) {
#pragma unroll
      for (int h = 0; h < 4; ++h) {
        srcv[h * 4096 + i] = s[h * 2] * LOG2E;
        float d = s[h * 2 + 1] * LOG2E;
        dstv[h * 4096 + i] = d;
        dstva[h * 4096 + i] = ALPHA * d;
      }
    }
  }
}

// ================= k_l2: gemm_wh L2 (128) + matvec2 (256) =================
__global__ void __launch_bounds__(256, 2)
k_l2(const unsigned short* __restrict__ h1, const unsigned short* __restrict__ w2t,
     unsigned short* __restrict__ whT2, const float* __restrict__ wa,
     float* __restrict__ srcv, float* __restrict__ dstv, float* __restrict__ dstva) {
  __shared__ char lds[49152];
  const int b = blockIdx.x;
  if (b < 128) {
    int i0 = (b & 63) * 64;
    int fbase = ((b >> 6) & 1) * 128;
    gemm_wh_body(h1, w2t, whT2, 1024, i0, fbase, lds);
    return;
  }
  // ---- matvec2 ----
  const int mb = b - 128;
  int lane = threadIdx.x & 63, wid = threadIdx.x >> 6;
  float wv[2][16];
#pragma unroll
  for (int v = 0; v < 2; ++v)
#pragma unroll
    for (int j = 0; j < 16; ++j) wv[v][j] = wa[v * 1024 + lane * 16 + j];
  int base = (mb * 4 + wid) * 4;
  for (int rr = 0; rr < 4; ++rr) {
    int i = base + rr;
    u16x8 x0 = *(const u16x8*)(h1 + (size_t)i * 1024 + lane * 16);
    u16x8 x1 = *(const u16x8*)(h1 + (size_t)i * 1024 + lane * 16 + 8);
    float s0 = 0.f, s1 = 0.f;
#pragma unroll
    for (int j = 0; j < 8; ++j) {
      float a0 = bf2f(x0[j]), a1 = bf2f(x1[j]);
      s0 += a0 * wv[0][j] + a1 * wv[0][j + 8];
      s1 += a0 * wv[1][j] + a1 * wv[1][j + 8];
    }
#pragma unroll
    for (int off = 32; off; off >>= 1) {
      s0 += __shfl_xor(s0, off);
      s1 += __shfl_xor(s1, off);
    }
    if (lane == 0) {
      srcv[i] = s0 * LOG2E;
      float d = s1 * LOG2E;
      dstv[i] = d;
      dstva[i] = ALPHA * d;
    }
  }
}

// ---------------- fused attention GEMM: R2/R9 k_attn4 structure (known-good 64.8 us) ----------------
// 4 waves, single-barrier counted-vmcnt pipeline; dmax in prologue. EXACT R9 revert:
// R10 proved occupancy at the same barrier structure doesn't help (8-wave = +9% slower)
// - limiter is per-step serial chain, and 4-wave has least arrival skew.
// LDS: Bs 2x32K + Ps 2x8K = exactly 80 KB -> 2 blocks/CU.

#define STAGE(PAR)                                                             \
  _Pragma("unroll")                                                            \
  for (int it = 0; it < 8; ++it)                                               \
    gl_lds16(wh_head + sidx + it * 131072u,                                    \
             (char*)&Bs[PAR][0] + (it * 256 + tid) * 16);                      \
  sidx += 64;

#define PREFETCH(DZ, DA, WB)                                                   \
  _Pragma("unroll")                                                            \
  for (int c4 = 0; c4 < 4; ++c4) {                                             \
    DZ[c4] = *(const f32x4*)(dzp + c4 * 4);                                    \
    DA[c4] = *(const f32x4*)(dap + c4 * 4);                                    \
  }                                                                            \
  WB = *browp;                                                                 \
  dzp += 64; dap += 64; browp += 2;

#define PCOMP(WB, DZ, DA)                                                      \
  {                                                                            \
    unsigned wbv = (WB >> shift) & 0xFFFFu;                                    \
    _Pragma("unroll")                                                          \
    for (int c8 = 0; c8 < 2; ++c8) {                                           \
      float pe[8];                                                             \
      _Pragma("unroll")                                                        \
      for (int jj = 0; jj < 8; ++jj) {                                         \
        float e = fmaxf(sm + DZ[c8 * 2 + (jj >> 2)][jj & 3],                   \
                        am + DA[c8 * 2 + (jj >> 2)][jj & 3]);                  \
        e = (wbv & (1u << (c8 * 8 + jj))) ? e : -1e30f;                        \
        pe[jj] = exp2_hw(e);                                                   \
      }                                                                        \
      u32x4 pv;                                                                \
      pv[0] = cvt_pk_bf16(pe[0], pe[1]);                                       \
      pv[1] = cvt_pk_bf16(pe[2], pe[3]);                                       \
      pv[2] = cvt_pk_bf16(pe[4], pe[5]);                                       \
      pv[3] = cvt_pk_bf16(pe[6], pe[7]);                                       \
      lsum += ((pe[0] + pe[1]) + (pe[2] + pe[3])) +                            \
              ((pe[4] + pe[5]) + (pe[6] + pe[7]));                             \
      if (c8) pvB = pv; else pvA = pv;                                         \
    }                                                                          \
  }

#define PSTO(PAR)                                                              \
  *(u32x4*)&Ps[PAR][prow * 64 + ((2 * kq + 0) ^ (prow & 7)) * 8] = pvA;        \
  *(u32x4*)&Ps[PAR][prow * 64 + ((2 * kq + 1) ^ (prow & 7)) * 8] = pvB;

#define DOMFMA(PAR)                                                            \
  {                                                                            \
    _Pragma("unroll")                                                          \
    for (int s = 0; s < 2; ++s) {                                              \
      bf16x8 af[4], bfr[4];                                                    \
      _Pragma("unroll")                                                        \
      for (int mi = 0; mi < 4; ++mi)                                           \
        af[mi] = *(const bf16x8*)&Ps[PAR][(mi * 16 + l15) * 64 +               \
                                          ((s * 4 + q) ^ (l15 & 7)) * 8];      \
      _Pragma("unroll")                                                        \
      for (int ni = 0; ni < 4; ++ni) {                                         \
        int f = wid * 64 + ni * 16 + l15;                                      \
        int slot = (s * 4 + q) ^ (l15 & 7);                                    \
        bfr[ni] = *(const bf16x8*)&Bs[PAR][f * 64 + slot * 8];                 \
      }                                                                        \
      __builtin_amdgcn_s_setprio(1);                                           \
      _Pragma("unroll")                                                        \
      for (int mi = 0; mi < 4; ++mi)                                           \
        _Pragma("unroll")                                                      \
        for (int ni = 0; ni < 4; ++ni)                                         \
          acc[mi][ni] = __builtin_amdgcn_mfma_f32_16x16x32_bf16(               \
              af[mi], bfr[ni], acc[mi][ni], 0, 0, 0);                          \
      __builtin_amdgcn_s_setprio(0);                                           \
    }                                                                          \
  }

#define STEP_SYNC                                                              \
  asm volatile("s_waitcnt vmcnt(9)" ::: "memory");                             \
  asm volatile("s_waitcnt lgkmcnt(0)" ::: "memory");                           \
  __builtin_amdgcn_sched_barrier(0);                                           \
  __builtin_amdgcn_s_barrier();                                                \
  __builtin_amdgcn_sched_barrier(0);

#define BODY(PAR, DZC, DAC, WBC, DZN, DAN, WBN)                                \
  {                                                                            \
    STAGE(PAR ^ 1)                                                             \
    __builtin_amdgcn_sched_barrier(0); /* keep stage older than prefetch */    \
    PREFETCH(DZN, DAN, WBN)                                                    \
    PCOMP(WBC, DZC, DAC)                                                       \
    DOMFMA(PAR)                                                                \
    PSTO(PAR ^ 1)                                                              \
    STEP_SYNC                                                                  \
  }

template <int JS, int H, int OC>
__global__ void __launch_bounds__(256, 2)
k_attn4(const unsigned short* __restrict__ whT, const unsigned int* __restrict__ bits,
        const float* __restrict__ srcv, const float* __restrict__ dstv,
        const float* __restrict__ dstva,
        float* __restrict__ Opart, float* __restrict__ Lpart) {
  static_assert(H * JS == 8, "group size must be 8");
  __shared__ unsigned short Bs[2][256 * 64];  // 64 KB, XOR-swizzled 16B chunks
  __shared__ unsigned short Ps[2][64 * 64];   // 16 KB, XOR-swizzled 16B chunks
  const int tid = threadIdx.x, lane = tid & 63, wid = tid >> 6;
  const int q = lane >> 4, l15 = lane & 15;
  const int bid = blockIdx.x;
  const int g = bid & 7;
  const int head = g & (H - 1);
  const int js = g / H;
  const int i0 = (bid >> 3) * 64;
  const int jbase = js * (4096 / JS);
  constexpr int JSTEPS = (4096 / JS) / 64;

  const unsigned short* wh_head = whT + (size_t)head * 256 * 4096;
  const int prow = tid & 63, kq = tid >> 6;

  // ---- dmax prologue: max over this head's dst ----
  float dmax;
  {
    float* dred = (float*)&Ps[0][0];   // Ps unused until PSTO(0)
    const float* dp = dstv + head * 4096;
    float lm = -1e30f;
#pragma unroll
    for (int k = 0; k < 4; ++k) {
      f32x4 v = *(const f32x4*)(dp + (tid + k * 256) * 4);
      lm = fmaxf(fmaxf(lm, fmaxf(v[0], v[1])), fmaxf(v[2], v[3]));
    }
#pragma unroll
    for (int off = 32; off; off >>= 1) lm = fmaxf(lm, __shfl_xor(lm, off));
    if (lane == 0) dred[wid] = lm;
    __syncthreads();
    dmax = fmaxf(fmaxf(dred[0], dred[1]), fmaxf(dred[2], dred[3]));
    __syncthreads();   // dred reads done before Ps is reused
  }

  float src_r = srcv[head * 4096 + i0 + prow];   // pre-scaled by log2e
  float m_r;
  { float xm = src_r + dmax; m_r = fmaxf(xm, ALPHA * xm); }
  const float sm = src_r - m_r;          // lrelu(s+d)-m = max(sm+d, am+alpha*d)
  const float am = ALPHA * src_r - m_r;
  float lsum = 0.f;
  f32x4 acc[4][4] = {};

  // 32-bit running offsets
  const int srow = tid >> 3;
  unsigned sidx = (unsigned)(srow * 4096 + jbase + ((tid & 7) ^ (srow & 7)) * 8);
  const float* dzp = dstv + head * 4096 + jbase + kq * 16;
  const float* dap = dstva + head * 4096 + jbase + kq * 16;
  const unsigned int* browp = bits + (size_t)(i0 + prow) * 128 + (jbase >> 5) + (kq >> 1);
  const int shift = (kq & 1) * 16;

  f32x4 dzA[4], daA[4], dzB[4], daB[4];
  unsigned wbA, wbB;
  u32x4 pvA, pvB;

  // ---- prologue: dz(0)->A, stage Bs[0], dz(1)->B, P(0)->Ps[0] ----
  PREFETCH(dzA, daA, wbA)
  __builtin_amdgcn_sched_barrier(0);
  STAGE(0)
  __builtin_amdgcn_sched_barrier(0);
  PREFETCH(dzB, daB, wbB)
  PCOMP(wbA, dzA, daA)   // waits dz(0); stage + dz(1) stay in flight
  PSTO(0)
  STEP_SYNC              // vmcnt(9): stage(0) done, dz(1) flying

  // ---- main loop: body T has parity T&1; JSTEPS-1 bodies total ----
  for (int t = 0; t < JSTEPS - 3; t += 2) {
    BODY(0, dzB, daB, wbB, dzA, daA, wbA)
    BODY(1, dzA, daA, wbA, dzB, daB, wbB)
  }
  BODY(0, dzB, daB, wbB, dzA, daA, wbA)  // T = JSTEPS-2 (even)
  DOMFMA(1)                              // final step, parity 1

  // ---- epilogue: row-sum partials + unnormalized O partials ----
  __syncthreads();
  float* Lred = (float*)&Ps[0][0];       // Ps dead after final DOMFMA
  Lred[kq * 64 + prow] = lsum;
  __syncthreads();
  if (tid < 64)
    Lpart[(size_t)(js * H + head) * 4096 + i0 + tid] =
        Lred[tid] + Lred[64 + tid] + Lred[128 + tid] + Lred[192 + tid];
  float* Ob = Opart + (size_t)js * 4096 * OC + head * 256;
#pragma unroll
  for (int mi = 0; mi < 4; ++mi)
#pragma unroll
    for (int ni = 0; ni < 4; ++ni) {
      int i = i0 + mi * 16 + q * 4;
      int col = wid * 64 + ni * 16 + l15;
#pragma unroll
      for (int r = 0; r < 4; ++r)
        Ob[(size_t)(i + r) * OC + col] = acc[mi][ni][r];
    }
}

// ---------------- combine layer1: h1 = ELU((Op0+Op1)/l) as bf16 ----------------
__global__ void __launch_bounds__(256) k_comb1(const float* __restrict__ Op,
                                               const float* __restrict__ Lp,
                                               unsigned short* __restrict__ h1) {
  int gidx = blockIdx.x * 256 + threadIdx.x;  // 1M threads, 4 cols each
  int i = gidx >> 8, c0 = (gidx & 255) * 4;
  int h = c0 >> 8;
  float l = Lp[h * 4096 + i] + Lp[(4 + h) * 4096 + i];
  float inv = 1.f / l;
  f32x4 p0 = *(const f32x4*)(Op + (size_t)i * 1024 + c0);
  f32x4 p1 = *(const f32x4*)(Op + (size_t)4096 * 1024 + (size_t)i * 1024 + c0);
  u16x4 o;
#pragma unroll
  for (int r = 0; r < 4; ++r) {
    float v = (p0[r] + p1[r]) * inv;
    v = v > 0.f ? v : (__expf(v) - 1.f);
    o[r] = f2bf(v);
  }
  *(u16x4*)(h1 + (size_t)i * 1024 + c0) = o;
}

// ---------------- combine layer2: out = (sum Op_js)/l, fp32 ----------------
__global__ void __launch_bounds__(256) k_comb2(const float* __restrict__ Op,
                                               const float* __restrict__ Lp,
                                               float* __restrict__ out) {
  int gidx = blockIdx.x * 256 + threadIdx.x;  // 262144 threads, 4 cols each
  int i = gidx >> 6, c0 = (gidx & 63) * 4;
  float l = 0.f;
#pragma unroll
  for (int js = 0; js < 8; ++js) l += Lp[js * 4096 + i];
  f32x4 s = {0.f, 0.f, 0.f, 0.f};
#pragma unroll
  for (int js = 0; js < 8; ++js)
    s += *(const f32x4*)(Op + (size_t)js * 4096 * 256 + (size_t)i * 256 + c0);
  float inv = 1.f / l;
  f32x4 o;
#pragma unroll
  for (int r = 0; r < 4; ++r) o[r] = s[r] * inv;
  *(f32x4*)(out + (size_t)i * 256 + c0) = o;
}

extern "C" void kernel_launch(void* const* d_in, const int* in_sizes, int n_in,
                              void* d_out, int out_size, void* d_ws, size_t ws_size,
                              hipStream_t stream) {
  const float* x  = (const float*)d_in[0];
  const int* adj  = (const int*)d_in[1];
  const float* W1 = (const float*)d_in[2];
  const float* a1 = (const float*)d_in[3];
  const float* W2 = (const float*)d_in[4];
  const float* a2 = (const float*)d_in[5];

  char* ws = (char*)d_ws;
  size_t off = 0;
  auto alloc = [&](size_t bytes) {
    void* p = ws + off;
    off = (off + bytes + 255) & ~(size_t)255;
    return p;
  };
  unsigned int*   bits = (unsigned int*)  alloc((size_t)4096 * 128 * 4);    //  2 MB
  unsigned short* xb   = (unsigned short*)alloc((size_t)4096 * 512 * 2);    //  4 MB
  unsigned short* w1t  = (unsigned short*)alloc((size_t)4 * 256 * 512 * 2); //  1 MB
  unsigned short* w2t  = (unsigned short*)alloc((size_t)256 * 1024 * 2);    // .5 MB
  unsigned short* whT1 = (unsigned short*)alloc((size_t)1024 * 4096 * 2);   //  8 MB
  unsigned short* h1   = (unsigned short*)alloc((size_t)4096 * 1024 * 2);   //  8 MB
  unsigned short* whT2 = (unsigned short*)alloc((size_t)256 * 4096 * 2);    //  2 MB
  float* wa1  = (float*)alloc((size_t)8 * 512 * 4);
  float* wa2  = (float*)alloc((size_t)2 * 1024 * 4);
  float* src1 = (float*)alloc(4 * 4096 * 4);
  float* dst1 = (float*)alloc(4 * 4096 * 4);
  float* dst1a = (float*)alloc(4 * 4096 * 4);
  float* src2 = (float*)alloc(4096 * 4);
  float* dst2 = (float*)alloc(4096 * 4);
  float* dst2a = (float*)alloc(4096 * 4);
  float* Lp1  = (float*)alloc((size_t)8 * 4096 * 4);
  float* Lp2  = (float*)alloc((size_t)8 * 4096 * 4);
  float* Opart = (float*)alloc((size_t)2 * 4096 * 1024 * 4);  // 32 MB, reused by layer 2

  // 1. prep (pack_bits FIRST + cast + transposes + wa)
  k_prep<<<dim3(PREP_GRID), dim3(256), 0, stream>>>(
      adj, bits, x, xb, W1, w1t, W2, w2t, a1, wa1, a2, wa2);

  // 2-4. layer 1
  k_l1<<<dim3(768), dim3(256), 0, stream>>>(xb, w1t, whT1, wa1, src1, dst1, dst1a);
  k_attn4<2, 4, 1024><<<dim3(512), dim3(256), 0, stream>>>(whT1, bits, src1, dst1, dst1a, Opart, Lp1);
  k_comb1<<<dim3(4096), dim3(256), 0, stream>>>(Opart, Lp1, h1);

  // 5-7. layer 2
  k_l2<<<dim3(384), dim3(256), 0, stream>>>(h1, w2t, whT2, wa2, src2, dst2, dst2a);
  k_attn4<8, 1, 256><<<dim3(512), dim3(256), 0, stream>>>(whT2, bits, src2, dst2, dst2a, Opart, Lp2);
  k_comb2<<<dim3(1024), dim3(256), 0, stream>>>(Opart, Lp2, (float*)d_out);
}

// Round 12
// 221.866 us; speedup vs baseline: 1.0561x; 1.0186x over previous
//
#include <hip/hip_runtime.h>
#include <hip/hip_bf16.h>
#include <stdint.h>

#define ALPHA 0.2f
#define LOG2E 1.4426950408889634f

typedef __attribute__((ext_vector_type(4))) float f32x4;
typedef __attribute__((ext_vector_type(8))) __bf16 bf16x8;
typedef __attribute__((ext_vector_type(8))) unsigned short u16x8;
typedef __attribute__((ext_vector_type(4))) unsigned short u16x4;
typedef __attribute__((ext_vector_type(4))) unsigned int u32x4;

static __device__ __forceinline__ unsigned short f2bf(float f) {
  unsigned u = __builtin_bit_cast(unsigned, f);
  u += 0x7FFFu + ((u >> 16) & 1u);   // RNE
  return (unsigned short)(u >> 16);
}
static __device__ __forceinline__ float bf2f(unsigned short h) {
  unsigned u = ((unsigned)h) << 16;
  return __builtin_bit_cast(float, u);
}
// raw v_exp_f32: computes 2^x (inputs are pre-scaled by log2e upstream)
static __device__ __forceinline__ float exp2_hw(float x) {
  float r; asm("v_exp_f32 %0, %1" : "=v"(r) : "v"(x)); return r;
}
// packed f32->bf16 RNE (no builtin on gfx950)
static __device__ __forceinline__ unsigned int cvt_pk_bf16(float lo, float hi) {
  unsigned int r; asm("v_cvt_pk_bf16_f32 %0, %1, %2" : "=v"(r) : "v"(lo), "v"(hi)); return r;
}
// async global->LDS, 16B per lane. LDS dest must be wave-uniform base + lane*16.
static __device__ __forceinline__ void gl_lds16(const void* g, void* lds) {
  __builtin_amdgcn_global_load_lds(
      (const __attribute__((address_space(1))) unsigned int*)g,
      (__attribute__((address_space(3))) unsigned int*)lds, 16, 0, 0);
}

// ================= k_prep: pack_bits + cast + transposes + wa =================
// pack_bits runs first (before whT1 exists) - R8/R9 ordering heuristic; note R11
// showed the attn delta may partly be cross-session variance, but first is safe.
#define PREP_PACK_END 16384
#define PREP_CAST_END 17408
#define PREP_T1_END   17920
#define PREP_T2_END   18176
#define PREP_WA1_END  18688
#define PREP_GRID     18944

__global__ void k_prep(const int* __restrict__ adj, unsigned int* __restrict__ bits,
                       const float* __restrict__ x, unsigned short* __restrict__ xb,
                       const float* __restrict__ W1, unsigned short* __restrict__ w1t,
                       const float* __restrict__ W2, unsigned short* __restrict__ w2t,
                       const float* __restrict__ a1, float* __restrict__ wa1,
                       const float* __restrict__ a2, float* __restrict__ wa2) {
  __shared__ float tsh[32][33];
  const int b = blockIdx.x, tid = threadIdx.x;
  if (b < PREP_PACK_END) {
    // ---- pack_bits: quarter-row per block ----
    int row = b >> 2, qo = b & 3;
    const int4* ap = (const int4*)(adj + (size_t)row * 4096 + qo * 1024);
    int4 v = ap[tid];
    unsigned n = (unsigned)(v.x != 0) | ((unsigned)(v.y != 0) << 1) |
                 ((unsigned)(v.z != 0) << 2) | ((unsigned)(v.w != 0) << 3);
    unsigned char* nib = (unsigned char*)tsh;
    nib[tid] = (unsigned char)n;
    __syncthreads();
    if (tid < 32) {
      unsigned w = 0;
#pragma unroll
      for (int s = 0; s < 8; ++s) w |= ((unsigned)nib[tid * 8 + s]) << (4 * s);
      bits[(size_t)row * 128 + qo * 32 + tid] = w;
    }
  } else if (b < PREP_CAST_END) {
    int t = (b - PREP_PACK_END) * 256 + tid;
    const f32x4* p = (const f32x4*)(x + (long)t * 8);
    f32x4 va = p[0], vb = p[1];
    u16x8 o;
#pragma unroll
    for (int k = 0; k < 4; ++k) { o[k] = f2bf(va[k]); o[k + 4] = f2bf(vb[k]); }
    *(u16x8*)(xb + (long)t * 8) = o;
  } else if (b < PREP_T2_END) {
    const float* in; unsigned short* out; int K, N, bx, by, bz;
    if (b < PREP_T1_END) {
      int idx = b - PREP_CAST_END;           // 512 blocks: (16,8,4)
      bx = idx & 15; by = (idx >> 4) & 7; bz = idx >> 7;
      in = W1; out = w1t; K = 512; N = 256;
    } else {
      int idx = b - PREP_T1_END;             // 256 blocks: (32,8,1)
      bx = idx & 31; by = (idx >> 5) & 7; bz = 0;
      in = W2; out = w2t; K = 1024; N = 256;
    }
    long bs = (long)K * N;
    const float* inb = in + bz * bs;
    unsigned short* outb = out + bz * bs;
    int k0 = bx * 32, n0 = by * 32;
    int tx = tid & 31, ty = tid >> 5;
#pragma unroll
    for (int it = 0; it < 4; ++it)
      tsh[ty + it * 8][tx] = inb[(long)(k0 + ty + it * 8) * N + n0 + tx];
    __syncthreads();
#pragma unroll
    for (int it = 0; it < 4; ++it)
      outb[(long)(n0 + ty + it * 8) * K + k0 + tx] = f2bf(tsh[tx][ty + it * 8]);
  } else {
    const float* W; const float* a; float* wa; int headK;
    int bl;
    if (b < PREP_WA1_END) { bl = b - PREP_T2_END; W = W1; a = a1; wa = wa1; headK = 512; }
    else                  { bl = b - PREP_WA1_END; W = W2; a = a2; wa = wa2; headK = 1024; }
    const int F = 256;
    int w = (bl * 256 + tid) >> 6;
    int lane = tid & 63;
    int h = w / headK, fl = w % headK;
    const float* row = W + (size_t)w * F;
    const float* ah = a + (size_t)h * 2 * F;
    float s0 = 0.f, s1 = 0.f;
    for (int fo = lane; fo < F; fo += 64) {
      float wv = row[fo];
      s0 += wv * ah[fo];
      s1 += wv * ah[F + fo];
    }
#pragma unroll
    for (int off = 32; off; off >>= 1) {
      s0 += __shfl_xor(s0, off);
      s1 += __shfl_xor(s1, off);
    }
    if (lane == 0) {
      wa[(size_t)(h * 2 + 0) * headK + fl] = s0;
      wa[(size_t)(h * 2 + 1) * headK + fl] = s1;
    }
  }
}

// ================= pipelined gemm_wh body, BK=64 (halved barrier count) =================
// A[4096,K]bf16 @ BT[f][K]bf16 -> whT[f][4096] bf16; block = 64 rows x 128 f.
// LDS 48 KB: As[2][64*64] @ 0/8192, Bs[2][128*64] @ 16384/32768.
// Layout = attn4's proven pattern: linear LDS dest, pre-swizzled global source
// (chunk ^= row&7), XOR-swizzled ds_read slot -> 2-way residual conflicts (free).
static __device__ __forceinline__ void gemm_wh_body(
    const unsigned short* __restrict__ A, const unsigned short* __restrict__ BT,
    unsigned short* __restrict__ whT, int K, int i0, int fbase, char* lds) {
  unsigned short* As = (unsigned short*)lds;            // 2 x 4096 shorts
  unsigned short* Bs = (unsigned short*)(lds + 16384);  // 2 x 8192 shorts
  const int tid = threadIdx.x, lane = tid & 63, wid = tid >> 6;
  const int q = lane >> 4, l15 = lane & 15;
  const int wm = wid >> 1, wn = wid & 1;
  f32x4 acc[2][4] = {};
  // stage sources, pre-swizzled chunk (c ^ row&7); LDS dest linear in thread order
  const int arow0 = tid >> 3, arow1 = arow0 + 32;
  const unsigned short* aSrc0 = A + (long)(i0 + arow0) * K + (((tid & 7) ^ (arow0 & 7)) * 8);
  const unsigned short* aSrc1 = A + (long)(i0 + arow1) * K + (((tid & 7) ^ (arow1 & 7)) * 8);
  const unsigned short* bSrc[4];
#pragma unroll
  for (int p = 0; p < 4; ++p) {
    int row = p * 32 + (tid >> 3);
    bSrc[p] = BT + (long)(fbase + row) * K + (((tid & 7) ^ (row & 7)) * 8);
  }

#define GSTAGE(PAR, KK)                                                        \
  gl_lds16(aSrc0 + (KK), lds + (PAR) * 8192 + tid * 16);                       \
  gl_lds16(aSrc1 + (KK), lds + (PAR) * 8192 + 4096 + tid * 16);                \
  _Pragma("unroll")                                                            \
  for (int p = 0; p < 4; ++p)                                                  \
    gl_lds16(bSrc[p] + (KK), lds + 16384 + (PAR) * 16384 + (p * 256 + tid) * 16);

  GSTAGE(0, 0)
  asm volatile("s_waitcnt vmcnt(0)" ::: "memory");
  __builtin_amdgcn_sched_barrier(0);
  __builtin_amdgcn_s_barrier();
  for (int kk = 0; kk < K; kk += 64) {
    const int par = (kk >> 6) & 1;
    if (kk + 64 < K) { GSTAGE(par ^ 1, kk + 64) }
#pragma unroll
    for (int s = 0; s < 2; ++s) {
      bf16x8 af[2], bfr[4];
#pragma unroll
      for (int mi = 0; mi < 2; ++mi) {
        int row = wm * 32 + mi * 16 + l15;
        af[mi] = *(const bf16x8*)&As[par * 4096 + row * 64 +
                                     (((s * 4 + q) ^ (l15 & 7)) * 8)];
      }
#pragma unroll
      for (int ni = 0; ni < 4; ++ni) {
        int f = wn * 64 + ni * 16 + l15;
        bfr[ni] = *(const bf16x8*)&Bs[par * 8192 + f * 64 +
                                      (((s * 4 + q) ^ (l15 & 7)) * 8)];
      }
      __builtin_amdgcn_s_setprio(1);
#pragma unroll
      for (int mi = 0; mi < 2; ++mi)
#pragma unroll
        for (int ni = 0; ni < 4; ++ni)
          acc[mi][ni] = __builtin_amdgcn_mfma_f32_16x16x32_bf16(af[mi], bfr[ni], acc[mi][ni], 0, 0, 0);
      __builtin_amdgcn_s_setprio(0);
    }
    asm volatile("s_waitcnt vmcnt(0)" ::: "memory");   // stage(t+1) landed
    asm volatile("s_waitcnt lgkmcnt(0)" ::: "memory");
    __builtin_amdgcn_sched_barrier(0);
    __builtin_amdgcn_s_barrier();
    __builtin_amdgcn_sched_barrier(0);
  }
#undef GSTAGE
#pragma unroll
  for (int mi = 0; mi < 2; ++mi)
#pragma unroll
    for (int ni = 0; ni < 4; ++ni) {
      int ig = i0 + wm * 32 + mi * 16 + q * 4;
      int fg = fbase + wn * 64 + ni * 16 + l15;
      u16x4 v;
#pragma unroll
      for (int r = 0; r < 4; ++r) v[r] = f2bf(acc[mi][ni][r]);
      *(u16x4*)&whT[(long)fg * 4096 + ig] = v;
    }
}

// ================= k_l1: gemm_wh L1 (512) + matvec1 (256) =================
__global__ void __launch_bounds__(256, 2)
k_l1(const unsigned short* __restrict__ xb, const unsigned short* __restrict__ w1t,
     unsigned short* __restrict__ whT1, const float* __restrict__ wa,
     float* __restrict__ srcv, float* __restrict__ dstv, float* __restrict__ dstva) {
  __shared__ char lds[49152];
  const int b = blockIdx.x, tid = threadIdx.x;
  if (b < 512) {
    int i0 = (b & 63) * 64;
    int fbase = (b >> 7) * 256 + ((b >> 6) & 1) * 128;
    gemm_wh_body(xb, w1t, whT1, 512, i0, fbase, lds);
    return;
  }
  // ---- matvec1: src/dst[h][i] = x[i,:] . wa[h*2+v], pre-scaled by log2e ----
  const int mb = b - 512;
  int lane = tid & 63, wid = tid >> 6;
  float wv[8][8];
#pragma unroll
  for (int v = 0; v < 8; ++v)
#pragma unroll
    for (int j = 0; j < 8; ++j) wv[v][j] = wa[v * 512 + lane * 8 + j];
  int base = (mb * 4 + wid) * 4;
  for (int rr = 0; rr < 4; ++rr) {
    int i = base + rr;
    u16x8 xv = *(const u16x8*)(xb + (size_t)i * 512 + lane * 8);
    float xf[8];
#pragma unroll
    for (int j = 0; j < 8; ++j) xf[j] = bf2f(xv[j]);
    float s[8] = {};
#pragma unroll
    for (int v = 0; v < 8; ++v)
#pragma unroll
      for (int j = 0; j < 8; ++j) s[v] += xf[j] * wv[v][j];
#pragma unroll
    for (int v = 0; v < 8; ++v)
#pragma unroll
      for (int off = 32; off; off >>= 1) s[v] += __shfl_xor(s[v], off);
    if (lane == 0) {
#pragma unroll
      for (int h = 0; h < 4; ++h) {
        srcv[h * 4096 + i] = s[h * 2] * LOG2E;
        float d = s[h * 2 + 1] * LOG2E;
        dstv[h * 4096 + i] = d;
        dstva[h * 4096 + i] = ALPHA * d;
      }
    }
  }
}

// ================= k_l2: gemm_wh L2 (128) + matvec2 (256) =================
__global__ void __launch_bounds__(256, 2)
k_l2(const unsigned short* __restrict__ h1, const unsigned short* __restrict__ w2t,
     unsigned short* __restrict__ whT2, const float* __restrict__ wa,
     float* __restrict__ srcv, float* __restrict__ dstv, float* __restrict__ dstva) {
  __shared__ char lds[49152];
  const int b = blockIdx.x;
  if (b < 128) {
    int i0 = (b & 63) * 64;
    int fbase = ((b >> 6) & 1) * 128;
    gemm_wh_body(h1, w2t, whT2, 1024, i0, fbase, lds);
    return;
  }
  // ---- matvec2 ----
  const int mb = b - 128;
  int lane = threadIdx.x & 63, wid = threadIdx.x >> 6;
  float wv[2][16];
#pragma unroll
  for (int v = 0; v < 2; ++v)
#pragma unroll
    for (int j = 0; j < 16; ++j) wv[v][j] = wa[v * 1024 + lane * 16 + j];
  int base = (mb * 4 + wid) * 4;
  for (int rr = 0; rr < 4; ++rr) {
    int i = base + rr;
    u16x8 x0 = *(const u16x8*)(h1 + (size_t)i * 1024 + lane * 16);
    u16x8 x1 = *(const u16x8*)(h1 + (size_t)i * 1024 + lane * 16 + 8);
    float s0 = 0.f, s1 = 0.f;
#pragma unroll
    for (int j = 0; j < 8; ++j) {
      float a0 = bf2f(x0[j]), a1 = bf2f(x1[j]);
      s0 += a0 * wv[0][j] + a1 * wv[0][j + 8];
      s1 += a0 * wv[1][j] + a1 * wv[1][j + 8];
    }
#pragma unroll
    for (int off = 32; off; off >>= 1) {
      s0 += __shfl_xor(s0, off);
      s1 += __shfl_xor(s1, off);
    }
    if (lane == 0) {
      srcv[i] = s0 * LOG2E;
      float d = s1 * LOG2E;
      dstv[i] = d;
      dstva[i] = ALPHA * d;
    }
  }
}

// ---------------- fused attention GEMM: R2/R9 k_attn4 structure ----------------
// 4 waves, single-barrier counted-vmcnt pipeline; dmax in prologue.
// OB16: layer-1 stores Opart as bf16 (numerator feeds the bf16 h1 path anyway;
// halves attn write + comb1 read traffic). Layer-2 keeps fp32 (error budget
// feeds the fp32 output directly).
// LDS: Bs 2x32K + Ps 2x8K = exactly 80 KB -> 2 blocks/CU.

#define STAGE(PAR)                                                             \
  _Pragma("unroll")                                                            \
  for (int it = 0; it < 8; ++it)                                               \
    gl_lds16(wh_head + sidx + it * 131072u,                                    \
             (char*)&Bs[PAR][0] + (it * 256 + tid) * 16);                      \
  sidx += 64;

#define PREFETCH(DZ, DA, WB)                                                   \
  _Pragma("unroll")                                                            \
  for (int c4 = 0; c4 < 4; ++c4) {                                             \
    DZ[c4] = *(const f32x4*)(dzp + c4 * 4);                                    \
    DA[c4] = *(const f32x4*)(dap + c4 * 4);                                    \
  }                                                                            \
  WB = *browp;                                                                 \
  dzp += 64; dap += 64; browp += 2;

#define PCOMP(WB, DZ, DA)                                                      \
  {                                                                            \
    unsigned wbv = (WB >> shift) & 0xFFFFu;                                    \
    _Pragma("unroll")                                                          \
    for (int c8 = 0; c8 < 2; ++c8) {                                           \
      float pe[8];                                                             \
      _Pragma("unroll")                                                        \
      for (int jj = 0; jj < 8; ++jj) {                                         \
        float e = fmaxf(sm + DZ[c8 * 2 + (jj >> 2)][jj & 3],                   \
                        am + DA[c8 * 2 + (jj >> 2)][jj & 3]);                  \
        e = (wbv & (1u << (c8 * 8 + jj))) ? e : -1e30f;                        \
        pe[jj] = exp2_hw(e);                                                   \
      }                                                                        \
      u32x4 pv;                                                                \
      pv[0] = cvt_pk_bf16(pe[0], pe[1]);                                       \
      pv[1] = cvt_pk_bf16(pe[2], pe[3]);                                       \
      pv[2] = cvt_pk_bf16(pe[4], pe[5]);                                       \
      pv[3] = cvt_pk_bf16(pe[6], pe[7]);                                       \
      lsum += ((pe[0] + pe[1]) + (pe[2] + pe[3])) +                            \
              ((pe[4] + pe[5]) + (pe[6] + pe[7]));                             \
      if (c8) pvB = pv; else pvA = pv;                                         \
    }                                                                          \
  }

#define PSTO(PAR)                                                              \
  *(u32x4*)&Ps[PAR][prow * 64 + ((2 * kq + 0) ^ (prow & 7)) * 8] = pvA;        \
  *(u32x4*)&Ps[PAR][prow * 64 + ((2 * kq + 1) ^ (prow & 7)) * 8] = pvB;

#define DOMFMA(PAR)                                                            \
  {                                                                            \
    _Pragma("unroll")                                                          \
    for (int s = 0; s < 2; ++s) {                                              \
      bf16x8 af[4], bfr[4];                                                    \
      _Pragma("unroll")                                                        \
      for (int mi = 0; mi < 4; ++mi)                                           \
        af[mi] = *(const bf16x8*)&Ps[PAR][(mi * 16 + l15) * 64 +               \
                                          ((s * 4 + q) ^ (l15 & 7)) * 8];      \
      _Pragma("unroll")                                                        \
      for (int ni = 0; ni < 4; ++ni) {                                         \
        int f = wid * 64 + ni * 16 + l15;                                      \
        int slot = (s * 4 + q) ^ (l15 & 7);                                    \
        bfr[ni] = *(const bf16x8*)&Bs[PAR][f * 64 + slot * 8];                 \
      }                                                                        \
      __builtin_amdgcn_s_setprio(1);                                           \
      _Pragma("unroll")                                                        \
      for (int mi = 0; mi < 4; ++mi)                                           \
        _Pragma("unroll")                                                      \
        for (int ni = 0; ni < 4; ++ni)                                         \
          acc[mi][ni] = __builtin_amdgcn_mfma_f32_16x16x32_bf16(               \
              af[mi], bfr[ni], acc[mi][ni], 0, 0, 0);                          \
      __builtin_amdgcn_s_setprio(0);                                           \
    }                                                                          \
  }

#define STEP_SYNC                                                              \
  asm volatile("s_waitcnt vmcnt(9)" ::: "memory");                             \
  asm volatile("s_waitcnt lgkmcnt(0)" ::: "memory");                           \
  __builtin_amdgcn_sched_barrier(0);                                           \
  __builtin_amdgcn_s_barrier();                                                \
  __builtin_amdgcn_sched_barrier(0);

#define BODY(PAR, DZC, DAC, WBC, DZN, DAN, WBN)                                \
  {                                                                            \
    STAGE(PAR ^ 1)                                                             \
    __builtin_amdgcn_sched_barrier(0); /* keep stage older than prefetch */    \
    PREFETCH(DZN, DAN, WBN)                                                    \
    PCOMP(WBC, DZC, DAC)                                                       \
    DOMFMA(PAR)                                                                \
    PSTO(PAR ^ 1)                                                              \
    STEP_SYNC                                                                  \
  }

template <int JS, int H, int OC, bool OB16>
__global__ void __launch_bounds__(256, 2)
k_attn4(const unsigned short* __restrict__ whT, const unsigned int* __restrict__ bits,
        const float* __restrict__ srcv, const float* __restrict__ dstv,
        const float* __restrict__ dstva,
        void* __restrict__ OpartV, float* __restrict__ Lpart) {
  static_assert(H * JS == 8, "group size must be 8");
  __shared__ unsigned short Bs[2][256 * 64];  // 64 KB, XOR-swizzled 16B chunks
  __shared__ unsigned short Ps[2][64 * 64];   // 16 KB, XOR-swizzled 16B chunks
  const int tid = threadIdx.x, lane = tid & 63, wid = tid >> 6;
  const int q = lane >> 4, l15 = lane & 15;
  const int bid = blockIdx.x;
  const int g = bid & 7;
  const int head = g & (H - 1);
  const int js = g / H;
  const int i0 = (bid >> 3) * 64;
  const int jbase = js * (4096 / JS);
  constexpr int JSTEPS = (4096 / JS) / 64;

  const unsigned short* wh_head = whT + (size_t)head * 256 * 4096;
  const int prow = tid & 63, kq = tid >> 6;

  // ---- dmax prologue: max over this head's dst ----
  float dmax;
  {
    float* dred = (float*)&Ps[0][0];   // Ps unused until PSTO(0)
    const float* dp = dstv + head * 4096;
    float lm = -1e30f;
#pragma unroll
    for (int k = 0; k < 4; ++k) {
      f32x4 v = *(const f32x4*)(dp + (tid + k * 256) * 4);
      lm = fmaxf(fmaxf(lm, fmaxf(v[0], v[1])), fmaxf(v[2], v[3]));
    }
#pragma unroll
    for (int off = 32; off; off >>= 1) lm = fmaxf(lm, __shfl_xor(lm, off));
    if (lane == 0) dred[wid] = lm;
    __syncthreads();
    dmax = fmaxf(fmaxf(dred[0], dred[1]), fmaxf(dred[2], dred[3]));
    __syncthreads();   // dred reads done before Ps is reused
  }

  float src_r = srcv[head * 4096 + i0 + prow];   // pre-scaled by log2e
  float m_r;
  { float xm = src_r + dmax; m_r = fmaxf(xm, ALPHA * xm); }
  const float sm = src_r - m_r;          // lrelu(s+d)-m = max(sm+d, am+alpha*d)
  const float am = ALPHA * src_r - m_r;
  float lsum = 0.f;
  f32x4 acc[4][4] = {};

  // 32-bit running offsets
  const int srow = tid >> 3;
  unsigned sidx = (unsigned)(srow * 4096 + jbase + ((tid & 7) ^ (srow & 7)) * 8);
  const float* dzp = dstv + head * 4096 + jbase + kq * 16;
  const float* dap = dstva + head * 4096 + jbase + kq * 16;
  const unsigned int* browp = bits + (size_t)(i0 + prow) * 128 + (jbase >> 5) + (kq >> 1);
  const int shift = (kq & 1) * 16;

  f32x4 dzA[4], daA[4], dzB[4], daB[4];
  unsigned wbA, wbB;
  u32x4 pvA, pvB;

  // ---- prologue: dz(0)->A, stage Bs[0], dz(1)->B, P(0)->Ps[0] ----
  PREFETCH(dzA, daA, wbA)
  __builtin_amdgcn_sched_barrier(0);
  STAGE(0)
  __builtin_amdgcn_sched_barrier(0);
  PREFETCH(dzB, daB, wbB)
  PCOMP(wbA, dzA, daA)   // waits dz(0); stage + dz(1) stay in flight
  PSTO(0)
  STEP_SYNC              // vmcnt(9): stage(0) done, dz(1) flying

  // ---- main loop: body T has parity T&1; JSTEPS-1 bodies total ----
  for (int t = 0; t < JSTEPS - 3; t += 2) {
    BODY(0, dzB, daB, wbB, dzA, daA, wbA)
    BODY(1, dzA, daA, wbA, dzB, daB, wbB)
  }
  BODY(0, dzB, daB, wbB, dzA, daA, wbA)  // T = JSTEPS-2 (even)
  DOMFMA(1)                              // final step, parity 1

  // ---- epilogue: row-sum partials + unnormalized O partials ----
  __syncthreads();
  float* Lred = (float*)&Ps[0][0];       // Ps dead after final DOMFMA
  Lred[kq * 64 + prow] = lsum;
  __syncthreads();
  if (tid < 64)
    Lpart[(size_t)(js * H + head) * 4096 + i0 + tid] =
        Lred[tid] + Lred[64 + tid] + Lred[128 + tid] + Lred[192 + tid];
  if constexpr (OB16) {
    unsigned short* Ob = (unsigned short*)OpartV + (size_t)js * 4096 * OC + head * 256;
#pragma unroll
    for (int mi = 0; mi < 4; ++mi)
#pragma unroll
      for (int ni = 0; ni < 4; ++ni) {
        int i = i0 + mi * 16 + q * 4;
        int col = wid * 64 + ni * 16 + l15;
#pragma unroll
        for (int r = 0; r < 4; ++r)
          Ob[(size_t)(i + r) * OC + col] = f2bf(acc[mi][ni][r]);
      }
  } else {
    float* Ob = (float*)OpartV + (size_t)js * 4096 * OC + head * 256;
#pragma unroll
    for (int mi = 0; mi < 4; ++mi)
#pragma unroll
      for (int ni = 0; ni < 4; ++ni) {
        int i = i0 + mi * 16 + q * 4;
        int col = wid * 64 + ni * 16 + l15;
#pragma unroll
        for (int r = 0; r < 4; ++r)
          Ob[(size_t)(i + r) * OC + col] = acc[mi][ni][r];
      }
  }
}

// ---------------- combine layer1: h1 = ELU((Op0+Op1)/l) as bf16 (bf16 Opart) ----------------
__global__ void __launch_bounds__(256) k_comb1(const unsigned short* __restrict__ Op,
                                               const float* __restrict__ Lp,
                                               unsigned short* __restrict__ h1) {
  int gidx = blockIdx.x * 256 + threadIdx.x;  // 1M threads, 4 cols each
  int i = gidx >> 8, c0 = (gidx & 255) * 4;
  int h = c0 >> 8;
  float l = Lp[h * 4096 + i] + Lp[(4 + h) * 4096 + i];
  float inv = 1.f / l;
  u16x4 p0 = *(const u16x4*)(Op + (size_t)i * 1024 + c0);
  u16x4 p1 = *(const u16x4*)(Op + (size_t)4096 * 1024 + (size_t)i * 1024 + c0);
  u16x4 o;
#pragma unroll
  for (int r = 0; r < 4; ++r) {
    float v = (bf2f(p0[r]) + bf2f(p1[r])) * inv;
    v = v > 0.f ? v : (__expf(v) - 1.f);
    o[r] = f2bf(v);
  }
  *(u16x4*)(h1 + (size_t)i * 1024 + c0) = o;
}

// ---------------- combine layer2: out = (sum Op_js)/l, fp32 ----------------
__global__ void __launch_bounds__(256) k_comb2(const float* __restrict__ Op,
                                               const float* __restrict__ Lp,
                                               float* __restrict__ out) {
  int gidx = blockIdx.x * 256 + threadIdx.x;  // 262144 threads, 4 cols each
  int i = gidx >> 6, c0 = (gidx & 63) * 4;
  float l = 0.f;
#pragma unroll
  for (int js = 0; js < 8; ++js) l += Lp[js * 4096 + i];
  f32x4 s = {0.f, 0.f, 0.f, 0.f};
#pragma unroll
  for (int js = 0; js < 8; ++js)
    s += *(const f32x4*)(Op + (size_t)js * 4096 * 256 + (size_t)i * 256 + c0);
  float inv = 1.f / l;
  f32x4 o;
#pragma unroll
  for (int r = 0; r < 4; ++r) o[r] = s[r] * inv;
  *(f32x4*)(out + (size_t)i * 256 + c0) = o;
}

extern "C" void kernel_launch(void* const* d_in, const int* in_sizes, int n_in,
                              void* d_out, int out_size, void* d_ws, size_t ws_size,
                              hipStream_t stream) {
  const float* x  = (const float*)d_in[0];
  const int* adj  = (const int*)d_in[1];
  const float* W1 = (const float*)d_in[2];
  const float* a1 = (const float*)d_in[3];
  const float* W2 = (const float*)d_in[4];
  const float* a2 = (const float*)d_in[5];

  char* ws = (char*)d_ws;
  size_t off = 0;
  auto alloc = [&](size_t bytes) {
    void* p = ws + off;
    off = (off + bytes + 255) & ~(size_t)255;
    return p;
  };
  unsigned int*   bits = (unsigned int*)  alloc((size_t)4096 * 128 * 4);    //  2 MB
  unsigned short* xb   = (unsigned short*)alloc((size_t)4096 * 512 * 2);    //  4 MB
  unsigned short* w1t  = (unsigned short*)alloc((size_t)4 * 256 * 512 * 2); //  1 MB
  unsigned short* w2t  = (unsigned short*)alloc((size_t)256 * 1024 * 2);    // .5 MB
  unsigned short* whT1 = (unsigned short*)alloc((size_t)1024 * 4096 * 2);   //  8 MB
  unsigned short* h1   = (unsigned short*)alloc((size_t)4096 * 1024 * 2);   //  8 MB
  unsigned short* whT2 = (unsigned short*)alloc((size_t)256 * 4096 * 2);    //  2 MB
  float* wa1  = (float*)alloc((size_t)8 * 512 * 4);
  float* wa2  = (float*)alloc((size_t)2 * 1024 * 4);
  float* src1 = (float*)alloc(4 * 4096 * 4);
  float* dst1 = (float*)alloc(4 * 4096 * 4);
  float* dst1a = (float*)alloc(4 * 4096 * 4);
  float* src2 = (float*)alloc(4096 * 4);
  float* dst2 = (float*)alloc(4096 * 4);
  float* dst2a = (float*)alloc(4096 * 4);
  float* Lp1  = (float*)alloc((size_t)8 * 4096 * 4);
  float* Lp2  = (float*)alloc((size_t)8 * 4096 * 4);
  void* Opart = alloc((size_t)8 * 4096 * 256 * 4);  // 32 MB (L2 fp32); L1 uses 16 MB bf16

  // 1. prep (pack_bits FIRST + cast + transposes + wa)
  k_prep<<<dim3(PREP_GRID), dim3(256), 0, stream>>>(
      adj, bits, x, xb, W1, w1t, W2, w2t, a1, wa1, a2, wa2);

  // 2-4. layer 1
  k_l1<<<dim3(768), dim3(256), 0, stream>>>(xb, w1t, whT1, wa1, src1, dst1, dst1a);
  k_attn4<2, 4, 1024, true><<<dim3(512), dim3(256), 0, stream>>>(whT1, bits, src1, dst1, dst1a, Opart, Lp1);
  k_comb1<<<dim3(4096), dim3(256), 0, stream>>>((const unsigned short*)Opart, Lp1, h1);

  // 5-7. layer 2
  k_l2<<<dim3(384), dim3(256), 0, stream>>>(h1, w2t, whT2, wa2, src2, dst2, dst2a);
  k_attn4<8, 1, 256, false><<<dim3(512), dim3(256), 0, stream>>>(whT2, bits, src2, dst2, dst2a, Opart, Lp2);
  k_comb2<<<dim3(1024), dim3(256), 0, stream>>>((const float*)Opart, Lp2, (float*)d_out);
}

// Round 13
// 208.146 us; speedup vs baseline: 1.1257x; 1.0659x over previous
//
#include <hip/hip_runtime.h>
#include <hip/hip_bf16.h>
#include <stdint.h>

#define ALPHA 0.2f
#define LOG2E 1.4426950408889634f

typedef __attribute__((ext_vector_type(4))) float f32x4;
typedef __attribute__((ext_vector_type(8))) __bf16 bf16x8;
typedef __attribute__((ext_vector_type(8))) unsigned short u16x8;
typedef __attribute__((ext_vector_type(4))) unsigned short u16x4;
typedef __attribute__((ext_vector_type(4))) unsigned int u32x4;

static __device__ __forceinline__ unsigned short f2bf(float f) {
  unsigned u = __builtin_bit_cast(unsigned, f);
  u += 0x7FFFu + ((u >> 16) & 1u);   // RNE
  return (unsigned short)(u >> 16);
}
static __device__ __forceinline__ float bf2f(unsigned short h) {
  unsigned u = ((unsigned)h) << 16;
  return __builtin_bit_cast(float, u);
}
// raw v_exp_f32: computes 2^x (inputs are pre-scaled by log2e upstream)
static __device__ __forceinline__ float exp2_hw(float x) {
  float r; asm("v_exp_f32 %0, %1" : "=v"(r) : "v"(x)); return r;
}
// packed f32->bf16 RNE (no builtin on gfx950)
static __device__ __forceinline__ unsigned int cvt_pk_bf16(float lo, float hi) {
  unsigned int r; asm("v_cvt_pk_bf16_f32 %0, %1, %2" : "=v"(r) : "v"(lo), "v"(hi)); return r;
}
// async global->LDS, 16B per lane. LDS dest must be wave-uniform base + lane*16.
static __device__ __forceinline__ void gl_lds16(const void* g, void* lds) {
  __builtin_amdgcn_global_load_lds(
      (const __attribute__((address_space(1))) unsigned int*)g,
      (__attribute__((address_space(3))) unsigned int*)lds, 16, 0, 0);
}

// ================= k_prep: pack_bits + cast + transposes + wa =================
// pack_bits runs first (before whT1 exists) - R8/R9 ordering heuristic.
#define PREP_PACK_END 16384
#define PREP_CAST_END 17408
#define PREP_T1_END   17920
#define PREP_T2_END   18176
#define PREP_WA1_END  18688
#define PREP_GRID     18944

__global__ void k_prep(const int* __restrict__ adj, unsigned int* __restrict__ bits,
                       const float* __restrict__ x, unsigned short* __restrict__ xb,
                       const float* __restrict__ W1, unsigned short* __restrict__ w1t,
                       const float* __restrict__ W2, unsigned short* __restrict__ w2t,
                       const float* __restrict__ a1, float* __restrict__ wa1,
                       const float* __restrict__ a2, float* __restrict__ wa2) {
  __shared__ float tsh[32][33];
  const int b = blockIdx.x, tid = threadIdx.x;
  if (b < PREP_PACK_END) {
    // ---- pack_bits: quarter-row per block ----
    int row = b >> 2, qo = b & 3;
    const int4* ap = (const int4*)(adj + (size_t)row * 4096 + qo * 1024);
    int4 v = ap[tid];
    unsigned n = (unsigned)(v.x != 0) | ((unsigned)(v.y != 0) << 1) |
                 ((unsigned)(v.z != 0) << 2) | ((unsigned)(v.w != 0) << 3);
    unsigned char* nib = (unsigned char*)tsh;
    nib[tid] = (unsigned char)n;
    __syncthreads();
    if (tid < 32) {
      unsigned w = 0;
#pragma unroll
      for (int s = 0; s < 8; ++s) w |= ((unsigned)nib[tid * 8 + s]) << (4 * s);
      bits[(size_t)row * 128 + qo * 32 + tid] = w;
    }
  } else if (b < PREP_CAST_END) {
    int t = (b - PREP_PACK_END) * 256 + tid;
    const f32x4* p = (const f32x4*)(x + (long)t * 8);
    f32x4 va = p[0], vb = p[1];
    u16x8 o;
#pragma unroll
    for (int k = 0; k < 4; ++k) { o[k] = f2bf(va[k]); o[k + 4] = f2bf(vb[k]); }
    *(u16x8*)(xb + (long)t * 8) = o;
  } else if (b < PREP_T2_END) {
    const float* in; unsigned short* out; int K, N, bx, by, bz;
    if (b < PREP_T1_END) {
      int idx = b - PREP_CAST_END;           // 512 blocks: (16,8,4)
      bx = idx & 15; by = (idx >> 4) & 7; bz = idx >> 7;
      in = W1; out = w1t; K = 512; N = 256;
    } else {
      int idx = b - PREP_T1_END;             // 256 blocks: (32,8,1)
      bx = idx & 31; by = (idx >> 5) & 7; bz = 0;
      in = W2; out = w2t; K = 1024; N = 256;
    }
    long bs = (long)K * N;
    const float* inb = in + bz * bs;
    unsigned short* outb = out + bz * bs;
    int k0 = bx * 32, n0 = by * 32;
    int tx = tid & 31, ty = tid >> 5;
#pragma unroll
    for (int it = 0; it < 4; ++it)
      tsh[ty + it * 8][tx] = inb[(long)(k0 + ty + it * 8) * N + n0 + tx];
    __syncthreads();
#pragma unroll
    for (int it = 0; it < 4; ++it)
      outb[(long)(n0 + ty + it * 8) * K + k0 + tx] = f2bf(tsh[tx][ty + it * 8]);
  } else {
    const float* W; const float* a; float* wa; int headK;
    int bl;
    if (b < PREP_WA1_END) { bl = b - PREP_T2_END; W = W1; a = a1; wa = wa1; headK = 512; }
    else                  { bl = b - PREP_WA1_END; W = W2; a = a2; wa = wa2; headK = 1024; }
    const int F = 256;
    int w = (bl * 256 + tid) >> 6;
    int lane = tid & 63;
    int h = w / headK, fl = w % headK;
    const float* row = W + (size_t)w * F;
    const float* ah = a + (size_t)h * 2 * F;
    float s0 = 0.f, s1 = 0.f;
    for (int fo = lane; fo < F; fo += 64) {
      float wv = row[fo];
      s0 += wv * ah[fo];
      s1 += wv * ah[F + fo];
    }
#pragma unroll
    for (int off = 32; off; off >>= 1) {
      s0 += __shfl_xor(s0, off);
      s1 += __shfl_xor(s1, off);
    }
    if (lane == 0) {
      wa[(size_t)(h * 2 + 0) * headK + fl] = s0;
      wa[(size_t)(h * 2 + 1) * headK + fl] = s1;
    }
  }
}

// ================= pipelined gemm_wh body, BK=64 =================
// A[4096,K]bf16 @ BT[f][K]bf16 -> whT[f][4096] bf16; block = 64 rows x 128 f.
// LDS 48 KB: As[2][64*64] @ 0/8192, Bs[2][128*64] @ 16384/32768.
// attn4's proven pattern: linear LDS dest, pre-swizzled global source
// (chunk ^= row&7), XOR-swizzled ds_read slot -> 2-way residual conflicts (free).
static __device__ __forceinline__ void gemm_wh_body(
    const unsigned short* __restrict__ A, const unsigned short* __restrict__ BT,
    unsigned short* __restrict__ whT, int K, int i0, int fbase, char* lds) {
  unsigned short* As = (unsigned short*)lds;            // 2 x 4096 shorts
  unsigned short* Bs = (unsigned short*)(lds + 16384);  // 2 x 8192 shorts
  const int tid = threadIdx.x, lane = tid & 63, wid = tid >> 6;
  const int q = lane >> 4, l15 = lane & 15;
  const int wm = wid >> 1, wn = wid & 1;
  f32x4 acc[2][4] = {};
  // stage sources, pre-swizzled chunk (c ^ row&7); LDS dest linear in thread order
  const int arow0 = tid >> 3, arow1 = arow0 + 32;
  const unsigned short* aSrc0 = A + (long)(i0 + arow0) * K + (((tid & 7) ^ (arow0 & 7)) * 8);
  const unsigned short* aSrc1 = A + (long)(i0 + arow1) * K + (((tid & 7) ^ (arow1 & 7)) * 8);
  const unsigned short* bSrc[4];
#pragma unroll
  for (int p = 0; p < 4; ++p) {
    int row = p * 32 + (tid >> 3);
    bSrc[p] = BT + (long)(fbase + row) * K + (((tid & 7) ^ (row & 7)) * 8);
  }

#define GSTAGE(PAR, KK)                                                        \
  gl_lds16(aSrc0 + (KK), lds + (PAR) * 8192 + tid * 16);                       \
  gl_lds16(aSrc1 + (KK), lds + (PAR) * 8192 + 4096 + tid * 16);                \
  _Pragma("unroll")                                                            \
  for (int p = 0; p < 4; ++p)                                                  \
    gl_lds16(bSrc[p] + (KK), lds + 16384 + (PAR) * 16384 + (p * 256 + tid) * 16);

  GSTAGE(0, 0)
  asm volatile("s_waitcnt vmcnt(0)" ::: "memory");
  __builtin_amdgcn_sched_barrier(0);
  __builtin_amdgcn_s_barrier();
  for (int kk = 0; kk < K; kk += 64) {
    const int par = (kk >> 6) & 1;
    if (kk + 64 < K) { GSTAGE(par ^ 1, kk + 64) }
#pragma unroll
    for (int s = 0; s < 2; ++s) {
      bf16x8 af[2], bfr[4];
#pragma unroll
      for (int mi = 0; mi < 2; ++mi) {
        int row = wm * 32 + mi * 16 + l15;
        af[mi] = *(const bf16x8*)&As[par * 4096 + row * 64 +
                                     (((s * 4 + q) ^ (l15 & 7)) * 8)];
      }
#pragma unroll
      for (int ni = 0; ni < 4; ++ni) {
        int f = wn * 64 + ni * 16 + l15;
        bfr[ni] = *(const bf16x8*)&Bs[par * 8192 + f * 64 +
                                      (((s * 4 + q) ^ (l15 & 7)) * 8)];
      }
      __builtin_amdgcn_s_setprio(1);
#pragma unroll
      for (int mi = 0; mi < 2; ++mi)
#pragma unroll
        for (int ni = 0; ni < 4; ++ni)
          acc[mi][ni] = __builtin_amdgcn_mfma_f32_16x16x32_bf16(af[mi], bfr[ni], acc[mi][ni], 0, 0, 0);
      __builtin_amdgcn_s_setprio(0);
    }
    asm volatile("s_waitcnt vmcnt(0)" ::: "memory");   // stage(t+1) landed
    asm volatile("s_waitcnt lgkmcnt(0)" ::: "memory");
    __builtin_amdgcn_sched_barrier(0);
    __builtin_amdgcn_s_barrier();
    __builtin_amdgcn_sched_barrier(0);
  }
#undef GSTAGE
#pragma unroll
  for (int mi = 0; mi < 2; ++mi)
#pragma unroll
    for (int ni = 0; ni < 4; ++ni) {
      int ig = i0 + wm * 32 + mi * 16 + q * 4;
      int fg = fbase + wn * 64 + ni * 16 + l15;
      u16x4 v;
#pragma unroll
      for (int r = 0; r < 4; ++r) v[r] = f2bf(acc[mi][ni][r]);
      *(u16x4*)&whT[(long)fg * 4096 + ig] = v;
    }
}

// ================= k_l1: gemm_wh L1 (512) + matvec1 (256) =================
__global__ void __launch_bounds__(256, 2)
k_l1(const unsigned short* __restrict__ xb, const unsigned short* __restrict__ w1t,
     unsigned short* __restrict__ whT1, const float* __restrict__ wa,
     float* __restrict__ srcv, float* __restrict__ dstv) {
  __shared__ char lds[49152];
  const int b = blockIdx.x, tid = threadIdx.x;
  if (b < 512) {
    int i0 = (b & 63) * 64;
    int fbase = (b >> 7) * 256 + ((b >> 6) & 1) * 128;
    gemm_wh_body(xb, w1t, whT1, 512, i0, fbase, lds);
    return;
  }
  // ---- matvec1: src/dst[h][i] = x[i,:] . wa[h*2+v], pre-scaled by log2e ----
  const int mb = b - 512;
  int lane = tid & 63, wid = tid >> 6;
  float wv[8][8];
#pragma unroll
  for (int v = 0; v < 8; ++v)
#pragma unroll
    for (int j = 0; j < 8; ++j) wv[v][j] = wa[v * 512 + lane * 8 + j];
  int base = (mb * 4 + wid) * 4;
  for (int rr = 0; rr < 4; ++rr) {
    int i = base + rr;
    u16x8 xv = *(const u16x8*)(xb + (size_t)i * 512 + lane * 8);
    float xf[8];
#pragma unroll
    for (int j = 0; j < 8; ++j) xf[j] = bf2f(xv[j]);
    float s[8] = {};
#pragma unroll
    for (int v = 0; v < 8; ++v)
#pragma unroll
      for (int j = 0; j < 8; ++j) s[v] += xf[j] * wv[v][j];
#pragma unroll
    for (int v = 0; v < 8; ++v)
#pragma unroll
      for (int off = 32; off; off >>= 1) s[v] += __shfl_xor(s[v], off);
    if (lane == 0) {
#pragma unroll
      for (int h = 0; h < 4; ++h) {
        srcv[h * 4096 + i] = s[h * 2] * LOG2E;
        dstv[h * 4096 + i] = s[h * 2 + 1] * LOG2E;
      }
    }
  }
}

// ================= k_l2: gemm_wh L2 (128) + matvec2 (256) =================
__global__ void __launch_bounds__(256, 2)
k_l2(const unsigned short* __restrict__ h1, const unsigned short* __restrict__ w2t,
     unsigned short* __restrict__ whT2, const float* __restrict__ wa,
     float* __restrict__ srcv, float* __restrict__ dstv) {
  __shared__ char lds[49152];
  const int b = blockIdx.x;
  if (b < 128) {
    int i0 = (b & 63) * 64;
    int fbase = ((b >> 6) & 1) * 128;
    gemm_wh_body(h1, w2t, whT2, 1024, i0, fbase, lds);
    return;
  }
  // ---- matvec2 ----
  const int mb = b - 128;
  int lane = threadIdx.x & 63, wid = threadIdx.x >> 6;
  float wv[2][16];
#pragma unroll
  for (int v = 0; v < 2; ++v)
#pragma unroll
    for (int j = 0; j < 16; ++j) wv[v][j] = wa[v * 1024 + lane * 16 + j];
  int base = (mb * 4 + wid) * 4;
  for (int rr = 0; rr < 4; ++rr) {
    int i = base + rr;
    u16x8 x0 = *(const u16x8*)(h1 + (size_t)i * 1024 + lane * 16);
    u16x8 x1 = *(const u16x8*)(h1 + (size_t)i * 1024 + lane * 16 + 8);
    float s0 = 0.f, s1 = 0.f;
#pragma unroll
    for (int j = 0; j < 8; ++j) {
      float a0 = bf2f(x0[j]), a1 = bf2f(x1[j]);
      s0 += a0 * wv[0][j] + a1 * wv[0][j + 8];
      s1 += a0 * wv[1][j] + a1 * wv[1][j + 8];
    }
#pragma unroll
    for (int off = 32; off; off >>= 1) {
      s0 += __shfl_xor(s0, off);
      s1 += __shfl_xor(s1, off);
    }
    if (lane == 0) {
      srcv[i] = s0 * LOG2E;
      dstv[i] = s1 * LOG2E;
    }
  }
}

// ---------------- fused attention GEMM: R2/R9 k_attn4 structure ----------------
// 4 waves, single-barrier counted-vmcnt pipeline; dmax in prologue.
// Opart stored bf16 for BOTH layers (R12 verified L1 at zero absmax cost; L2
// adds <= ~1.5e-3 per the signed-partial analysis, threshold 4.79e-3).
// dstva stream deleted: alpha*d recomputed via fmaf (more precise, halves
// prefetch to 5 in-flight loads -> vmcnt(5)).
// LDS: Bs 2x32K + Ps 2x8K = exactly 80 KB -> 2 blocks/CU.

#define STAGE(PAR)                                                             \
  _Pragma("unroll")                                                            \
  for (int it = 0; it < 8; ++it)                                               \
    gl_lds16(wh_head + sidx + it * 131072u,                                    \
             (char*)&Bs[PAR][0] + (it * 256 + tid) * 16);                      \
  sidx += 64;

#define PREFETCH(DZ, WB)                                                       \
  _Pragma("unroll")                                                            \
  for (int c4 = 0; c4 < 4; ++c4) DZ[c4] = *(const f32x4*)(dzp + c4 * 4);       \
  WB = *browp;                                                                 \
  dzp += 64; browp += 2;

#define PCOMP(WB, DZ)                                                          \
  {                                                                            \
    unsigned wbv = (WB >> shift) & 0xFFFFu;                                    \
    _Pragma("unroll")                                                          \
    for (int c8 = 0; c8 < 2; ++c8) {                                           \
      float pe[8];                                                             \
      _Pragma("unroll")                                                        \
      for (int jj = 0; jj < 8; ++jj) {                                         \
        float d = DZ[c8 * 2 + (jj >> 2)][jj & 3];                              \
        float e = fmaxf(sm + d, fmaf(ALPHA, d, am));                           \
        e = (wbv & (1u << (c8 * 8 + jj))) ? e : -1e30f;                        \
        pe[jj] = exp2_hw(e);                                                   \
      }                                                                        \
      u32x4 pv;                                                                \
      pv[0] = cvt_pk_bf16(pe[0], pe[1]);                                       \
      pv[1] = cvt_pk_bf16(pe[2], pe[3]);                                       \
      pv[2] = cvt_pk_bf16(pe[4], pe[5]);                                       \
      pv[3] = cvt_pk_bf16(pe[6], pe[7]);                                       \
      lsum += ((pe[0] + pe[1]) + (pe[2] + pe[3])) +                            \
              ((pe[4] + pe[5]) + (pe[6] + pe[7]));                             \
      if (c8) pvB = pv; else pvA = pv;                                         \
    }                                                                          \
  }

#define PSTO(PAR)                                                              \
  *(u32x4*)&Ps[PAR][prow * 64 + ((2 * kq + 0) ^ (prow & 7)) * 8] = pvA;        \
  *(u32x4*)&Ps[PAR][prow * 64 + ((2 * kq + 1) ^ (prow & 7)) * 8] = pvB;

#define DOMFMA(PAR)                                                            \
  {                                                                            \
    _Pragma("unroll")                                                          \
    for (int s = 0; s < 2; ++s) {                                              \
      bf16x8 af[4], bfr[4];                                                    \
      _Pragma("unroll")                                                        \
      for (int mi = 0; mi < 4; ++mi)                                           \
        af[mi] = *(const bf16x8*)&Ps[PAR][(mi * 16 + l15) * 64 +               \
                                          ((s * 4 + q) ^ (l15 & 7)) * 8];      \
      _Pragma("unroll")                                                        \
      for (int ni = 0; ni < 4; ++ni) {                                         \
        int f = wid * 64 + ni * 16 + l15;                                      \
        int slot = (s * 4 + q) ^ (l15 & 7);                                    \
        bfr[ni] = *(const bf16x8*)&Bs[PAR][f * 64 + slot * 8];                 \
      }                                                                        \
      __builtin_amdgcn_s_setprio(1);                                           \
      _Pragma("unroll")                                                        \
      for (int mi = 0; mi < 4; ++mi)                                           \
        _Pragma("unroll")                                                      \
        for (int ni = 0; ni < 4; ++ni)                                         \
          acc[mi][ni] = __builtin_amdgcn_mfma_f32_16x16x32_bf16(               \
              af[mi], bfr[ni], acc[mi][ni], 0, 0, 0);                          \
      __builtin_amdgcn_s_setprio(0);                                           \
    }                                                                          \
  }

#define STEP_SYNC                                                              \
  asm volatile("s_waitcnt vmcnt(5)" ::: "memory");                             \
  asm volatile("s_waitcnt lgkmcnt(0)" ::: "memory");                           \
  __builtin_amdgcn_sched_barrier(0);                                           \
  __builtin_amdgcn_s_barrier();                                                \
  __builtin_amdgcn_sched_barrier(0);

#define BODY(PAR, DZC, WBC, DZN, WBN)                                          \
  {                                                                            \
    STAGE(PAR ^ 1)                                                             \
    __builtin_amdgcn_sched_barrier(0); /* keep stage older than prefetch */    \
    PREFETCH(DZN, WBN)                                                         \
    PCOMP(WBC, DZC)                                                            \
    DOMFMA(PAR)                                                                \
    PSTO(PAR ^ 1)                                                              \
    STEP_SYNC                                                                  \
  }

template <int JS, int H, int OC>
__global__ void __launch_bounds__(256, 2)
k_attn4(const unsigned short* __restrict__ whT, const unsigned int* __restrict__ bits,
        const float* __restrict__ srcv, const float* __restrict__ dstv,
        unsigned short* __restrict__ Opart, float* __restrict__ Lpart) {
  static_assert(H * JS == 8, "group size must be 8");
  __shared__ unsigned short Bs[2][256 * 64];  // 64 KB, XOR-swizzled 16B chunks
  __shared__ unsigned short Ps[2][64 * 64];   // 16 KB, XOR-swizzled 16B chunks
  const int tid = threadIdx.x, lane = tid & 63, wid = tid >> 6;
  const int q = lane >> 4, l15 = lane & 15;
  const int bid = blockIdx.x;
  const int g = bid & 7;
  const int head = g & (H - 1);
  const int js = g / H;
  const int i0 = (bid >> 3) * 64;
  const int jbase = js * (4096 / JS);
  constexpr int JSTEPS = (4096 / JS) / 64;

  const unsigned short* wh_head = whT + (size_t)head * 256 * 4096;
  const int prow = tid & 63, kq = tid >> 6;

  // ---- dmax prologue: max over this head's dst ----
  float dmax;
  {
    float* dred = (float*)&Ps[0][0];   // Ps unused until PSTO(0)
    const float* dp = dstv + head * 4096;
    float lm = -1e30f;
#pragma unroll
    for (int k = 0; k < 4; ++k) {
      f32x4 v = *(const f32x4*)(dp + (tid + k * 256) * 4);
      lm = fmaxf(fmaxf(lm, fmaxf(v[0], v[1])), fmaxf(v[2], v[3]));
    }
#pragma unroll
    for (int off = 32; off; off >>= 1) lm = fmaxf(lm, __shfl_xor(lm, off));
    if (lane == 0) dred[wid] = lm;
    __syncthreads();
    dmax = fmaxf(fmaxf(dred[0], dred[1]), fmaxf(dred[2], dred[3]));
    __syncthreads();   // dred reads done before Ps is reused
  }

  float src_r = srcv[head * 4096 + i0 + prow];   // pre-scaled by log2e
  float m_r;
  { float xm = src_r + dmax; m_r = fmaxf(xm, ALPHA * xm); }
  const float sm = src_r - m_r;          // lrelu(s+d)-m = max(sm+d, am+alpha*d)
  const float am = ALPHA * src_r - m_r;
  float lsum = 0.f;
  f32x4 acc[4][4] = {};

  // 32-bit running offsets
  const int srow = tid >> 3;
  unsigned sidx = (unsigned)(srow * 4096 + jbase + ((tid & 7) ^ (srow & 7)) * 8);
  const float* dzp = dstv + head * 4096 + jbase + kq * 16;
  const unsigned int* browp = bits + (size_t)(i0 + prow) * 128 + (jbase >> 5) + (kq >> 1);
  const int shift = (kq & 1) * 16;

  f32x4 dzA[4], dzB[4];
  unsigned wbA, wbB;
  u32x4 pvA, pvB;

  // ---- prologue: dz(0)->A, stage Bs[0], dz(1)->B, P(0)->Ps[0] ----
  PREFETCH(dzA, wbA)
  __builtin_amdgcn_sched_barrier(0);
  STAGE(0)
  __builtin_amdgcn_sched_barrier(0);
  PREFETCH(dzB, wbB)
  PCOMP(wbA, dzA)        // waits dz(0); stage + dz(1) stay in flight
  PSTO(0)
  STEP_SYNC              // vmcnt(5): stage(0) done, dz(1) flying

  // ---- main loop: body T has parity T&1; JSTEPS-1 bodies total ----
  for (int t = 0; t < JSTEPS - 3; t += 2) {
    BODY(0, dzB, wbB, dzA, wbA)
    BODY(1, dzA, wbA, dzB, wbB)
  }
  BODY(0, dzB, wbB, dzA, wbA)  // T = JSTEPS-2 (even)
  DOMFMA(1)                    // final step, parity 1

  // ---- epilogue: row-sum partials + unnormalized O partials (bf16) ----
  __syncthreads();
  float* Lred = (float*)&Ps[0][0];       // Ps dead after final DOMFMA
  Lred[kq * 64 + prow] = lsum;
  __syncthreads();
  if (tid < 64)
    Lpart[(size_t)(js * H + head) * 4096 + i0 + tid] =
        Lred[tid] + Lred[64 + tid] + Lred[128 + tid] + Lred[192 + tid];
  unsigned short* Ob = Opart + (size_t)js * 4096 * OC + head * 256;
#pragma unroll
  for (int mi = 0; mi < 4; ++mi)
#pragma unroll
    for (int ni = 0; ni < 4; ++ni) {
      int i = i0 + mi * 16 + q * 4;
      int col = wid * 64 + ni * 16 + l15;
#pragma unroll
      for (int r = 0; r < 4; ++r)
        Ob[(size_t)(i + r) * OC + col] = f2bf(acc[mi][ni][r]);
    }
}

// ---------------- combine layer1: h1 = ELU((Op0+Op1)/l) as bf16 (bf16 Opart) ----------------
__global__ void __launch_bounds__(256) k_comb1(const unsigned short* __restrict__ Op,
                                               const float* __restrict__ Lp,
                                               unsigned short* __restrict__ h1) {
  int gidx = blockIdx.x * 256 + threadIdx.x;  // 1M threads, 4 cols each
  int i = gidx >> 8, c0 = (gidx & 255) * 4;
  int h = c0 >> 8;
  float l = Lp[h * 4096 + i] + Lp[(4 + h) * 4096 + i];
  float inv = 1.f / l;
  u16x4 p0 = *(const u16x4*)(Op + (size_t)i * 1024 + c0);
  u16x4 p1 = *(const u16x4*)(Op + (size_t)4096 * 1024 + (size_t)i * 1024 + c0);
  u16x4 o;
#pragma unroll
  for (int r = 0; r < 4; ++r) {
    float v = (bf2f(p0[r]) + bf2f(p1[r])) * inv;
    v = v > 0.f ? v : (__expf(v) - 1.f);
    o[r] = f2bf(v);
  }
  *(u16x4*)(h1 + (size_t)i * 1024 + c0) = o;
}

// ---------------- combine layer2: out = (sum Op_js)/l, fp32 out (bf16 Opart) ----------------
__global__ void __launch_bounds__(256) k_comb2(const unsigned short* __restrict__ Op,
                                               const float* __restrict__ Lp,
                                               float* __restrict__ out) {
  int gidx = blockIdx.x * 256 + threadIdx.x;  // 262144 threads, 4 cols each
  int i = gidx >> 6, c0 = (gidx & 63) * 4;
  float l = 0.f;
#pragma unroll
  for (int js = 0; js < 8; ++js) l += Lp[js * 4096 + i];
  f32x4 s = {0.f, 0.f, 0.f, 0.f};
#pragma unroll
  for (int js = 0; js < 8; ++js) {
    u16x4 p = *(const u16x4*)(Op + (size_t)js * 4096 * 256 + (size_t)i * 256 + c0);
#pragma unroll
    for (int r = 0; r < 4; ++r) s[r] += bf2f(p[r]);
  }
  float inv = 1.f / l;
  f32x4 o;
#pragma unroll
  for (int r = 0; r < 4; ++r) o[r] = s[r] * inv;
  *(f32x4*)(out + (size_t)i * 256 + c0) = o;
}

extern "C" void kernel_launch(void* const* d_in, const int* in_sizes, int n_in,
                              void* d_out, int out_size, void* d_ws, size_t ws_size,
                              hipStream_t stream) {
  const float* x  = (const float*)d_in[0];
  const int* adj  = (const int*)d_in[1];
  const float* W1 = (const float*)d_in[2];
  const float* a1 = (const float*)d_in[3];
  const float* W2 = (const float*)d_in[4];
  const float* a2 = (const float*)d_in[5];

  char* ws = (char*)d_ws;
  size_t off = 0;
  auto alloc = [&](size_t bytes) {
    void* p = ws + off;
    off = (off + bytes + 255) & ~(size_t)255;
    return p;
  };
  unsigned int*   bits = (unsigned int*)  alloc((size_t)4096 * 128 * 4);    //  2 MB
  unsigned short* xb   = (unsigned short*)alloc((size_t)4096 * 512 * 2);    //  4 MB
  unsigned short* w1t  = (unsigned short*)alloc((size_t)4 * 256 * 512 * 2); //  1 MB
  unsigned short* w2t  = (unsigned short*)alloc((size_t)256 * 1024 * 2);    // .5 MB
  unsigned short* whT1 = (unsigned short*)alloc((size_t)1024 * 4096 * 2);   //  8 MB
  unsigned short* h1   = (unsigned short*)alloc((size_t)4096 * 1024 * 2);   //  8 MB
  unsigned short* whT2 = (unsigned short*)alloc((size_t)256 * 4096 * 2);    //  2 MB
  float* wa1  = (float*)alloc((size_t)8 * 512 * 4);
  float* wa2  = (float*)alloc((size_t)2 * 1024 * 4);
  float* src1 = (float*)alloc(4 * 4096 * 4);
  float* dst1 = (float*)alloc(4 * 4096 * 4);
  float* src2 = (float*)alloc(4096 * 4);
  float* dst2 = (float*)alloc(4096 * 4);
  float* Lp1  = (float*)alloc((size_t)8 * 4096 * 4);
  float* Lp2  = (float*)alloc((size_t)8 * 4096 * 4);
  unsigned short* Opart = (unsigned short*)alloc((size_t)8 * 4096 * 256 * 2);  // 16 MB bf16

  // 1. prep (pack_bits FIRST + cast + transposes + wa)
  k_prep<<<dim3(PREP_GRID), dim3(256), 0, stream>>>(
      adj, bits, x, xb, W1, w1t, W2, w2t, a1, wa1, a2, wa2);

  // 2-4. layer 1
  k_l1<<<dim3(768), dim3(256), 0, stream>>>(xb, w1t, whT1, wa1, src1, dst1);
  k_attn4<2, 4, 1024><<<dim3(512), dim3(256), 0, stream>>>(whT1, bits, src1, dst1, Opart, Lp1);
  k_comb1<<<dim3(4096), dim3(256), 0, stream>>>(Opart, Lp1, h1);

  // 5-7. layer 2
  k_l2<<<dim3(384), dim3(256), 0, stream>>>(h1, w2t, whT2, wa2, src2, dst2);
  k_attn4<8, 1, 256><<<dim3(512), dim3(256), 0, stream>>>(whT2, bits, src2, dst2, Opart, Lp2);
  k_comb2<<<dim3(1024), dim3(256), 0, stream>>>(Opart, Lp2, (float*)d_out);
}